// Round 4
// baseline (319.285 us; speedup 1.0000x reference)
//
#include <hip/hip_runtime.h>
#include <hip/hip_bf16.h>
#include <hip/hip_cooperative_groups.h>

namespace cg = cooperative_groups;

// NSA forward, MI355X round 14. All inputs fp32, output fp32.
// r13 fused into ONE cooperative kernel (grid 256 x 512, 1 block/CU,
// 3 grid.sync()): phase A = prep+compress, B = cmp attention (2 old blocks
// per mega-block, shared Kc/Vc stage), C = slc/win MFMA attention (r13
// logic unchanged), D = merge. Tests the ~80us inter-kernel-gap theory:
// non-attn time was ~110us across r10-r13 regardless of kernel changes.
// Fallback to the 4-kernel path if cooperative launch fails.
// Shapes: S=4096, seqlen=2048, qh=8, kvh=2, dim=128, blk=64, TOPK=16,
// window=(512,0).

#define SEQ   2048
#define NB    2
#define KV    2
#define NH    4
#define QH    8
#define DIM   128
#define NBLK  32
#define NQB   32
#define NTOP  16
#define SCALE 0.08838834764831845f   // 128^-0.5
#define QSC   0.12751831795244785f   // SCALE * log2(e)
#define QS    36                     // cmp LDS quarter stride (floats)
#define RS    144                    // cmp LDS row stride
#define PLS   33                     // cmp P LDS row stride (floats)
#define VP    72                     // P/prep-T LDS row stride (bf16): pad 8

typedef unsigned short ushort_t;
using bf16x8 = __attribute__((ext_vector_type(8))) short;
using f32x4  = __attribute__((ext_vector_type(4))) float;

__device__ __forceinline__ unsigned pkbf(float a, float b){
  union { __hip_bfloat162 h; unsigned u; } cv;
  cv.h = __float22bfloat162_rn(make_float2(a, b));
  return cv.u;
}

// async 16B direct-to-LDS copy (per-lane global src, wave-uniform LDS base)
__device__ __forceinline__ void async16(ushort_t* l, const ushort_t* g){
  __builtin_amdgcn_global_load_lds(
      (const __attribute__((address_space(1))) unsigned int*)(size_t)g,
      (__attribute__((address_space(3))) unsigned int*)(size_t)l,
      16, 0, 0);
}

// ---- LDS overlays (union = max(~18, ~54, ~101) KB = 101.1 KB) --------------
struct ShA {
  ushort_t T[64*VP];                 // transpose tile
  float wks[64], wvs[64];
  float accK[16][64], accV[16][64];
};
struct ShB {
  float Ks[32*RS];
  float Vs[32*RS];
  float Pl[2][64*PLS];               // per-half P
};
struct ShC {
  ushort_t Ks[2][64*128];            // K dbuf (linear + pre-swizzled src)
  ushort_t VTs[2][128*64];           // VT dbuf
  ushort_t Ps[256*VP];               // per-wave 32-row P slabs
  float gbuf[256];
  int idxs[NTOP];
};
union ShU { ShA a; ShB b; ShC c; };

// ============================ mono kernel ===================================
__global__ __launch_bounds__(512, 2) void nsa_mono(
    const float* __restrict__ q, const float* __restrict__ k,
    const float* __restrict__ v,
    const float* __restrict__ w_k, const float* __restrict__ b_k,
    const float* __restrict__ w_v, const float* __restrict__ b_v,
    const float* __restrict__ w_gate, const float* __restrict__ b_gate,
    float* __restrict__ Kc, float* __restrict__ Vc, float* __restrict__ pp,
    float* __restrict__ slcbuf,
    ushort_t* __restrict__ Kb, ushort_t* __restrict__ VT,
    float* __restrict__ out)
{
  cg::grid_group grid = cg::this_grid();
  __shared__ ShU sh;
  int bm = blockIdx.x;
  int tid = threadIdx.x;

  // ======== phase A: K/V bf16 prep (swizzled Kb/VT) + block compression =====
  {
    int db = bm & 1, rb = (bm >> 1) & 31, bbg = bm >> 6;
    int bb = bbg >> 1, g = bbg & 1;
    if (tid < 64){ sh.a.wks[tid] = w_k[tid]; sh.a.wvs[tid] = w_v[tid]; }
    __syncthreads();
    if (tid < 256){
      float4 sk = {0,0,0,0}, sv = {0,0,0,0};
      for (int jj = 0; jj < 4; ++jj){
        int i = tid + jj*256;               // 1024 float4 units (64 rows x 16)
        int r = i >> 4, ds = i & 15;
        size_t src = ((size_t)(bb*SEQ + rb*64 + r)*KV + g)*DIM + db*64 + ds*4;
        float4 kx = *(const float4*)(k + src);
        float4 vx = *(const float4*)(v + src);
        uint2 kk; kk.x = pkbf(kx.x,kx.y); kk.y = pkbf(kx.z,kx.w);
        size_t rowb = ((size_t)bbg*SEQ + rb*64 + r)*DIM*2;    // row base bytes
        int swz = (db*128 + ds*8) ^ ((r & 7) << 4);           // within-row
        *(uint2*)((char*)Kb + rowb + swz) = kk;
        unsigned v01 = pkbf(vx.x,vx.y), v23 = pkbf(vx.z,vx.w);
        sh.a.T[(ds*4+0)*VP + r] = (ushort_t)(v01 & 0xffffu);
        sh.a.T[(ds*4+1)*VP + r] = (ushort_t)(v01 >> 16);
        sh.a.T[(ds*4+2)*VP + r] = (ushort_t)(v23 & 0xffffu);
        sh.a.T[(ds*4+3)*VP + r] = (ushort_t)(v23 >> 16);
        float a = sh.a.wks[r], b = sh.a.wvs[r];
        sk.x += a*kx.x; sk.y += a*kx.y; sk.z += a*kx.z; sk.w += a*kx.w;
        sv.x += b*vx.x; sv.y += b*vx.y; sv.z += b*vx.z; sv.w += b*vx.w;
      }
      *(float4*)&sh.a.accK[tid>>4][(tid&15)*4] = sk;
      *(float4*)&sh.a.accV[tid>>4][(tid&15)*4] = sv;
    }
    __syncthreads();
    if (tid < 256){
      for (int jj = 0; jj < 4; ++jj){
        int i = tid + jj*256;               // 1024 8B units (64 d x 16)
        int d = i >> 4, seg = i & 15;
        uint2 u = *(uint2*)&sh.a.T[d*VP + seg*4];
        size_t rowb = ((size_t)bbg*DIM + db*64 + d)*SEQ*2;    // d-row bytes
        int swz = (seg*8) ^ ((d & 7) << 4);                   // 128B-tile XOR
        *(uint2*)((char*)VT + rowb + rb*128 + swz) = u;
      }
      size_t obase = ((size_t)(bbg*NBLK + rb))*DIM + db*64;
      if (tid < 64){
        float s = 0.f;
#pragma unroll
        for (int i = 0; i < 16; ++i) s += sh.a.accK[i][tid];
        Kc[obase + tid] = s + b_k[0];
      } else if (tid < 128){
        int d = tid - 64;
        float s = 0.f;
#pragma unroll
        for (int i = 0; i < 16; ++i) s += sh.a.accV[i][d];
        Vc[obase + d] = s + b_v[0];
      }
    }
  }
  grid.sync();

  // ======== phase B: compressed attention (2 old blocks per mega-block) =====
  {
    int s = tid >> 8, tid2 = tid & 255;
    int hh = bm & 1, qb = (bm >> 1) & 31, g = (bm >> 6) & 1, bb = bm >> 7;
    int h = hh*2 + s;

    const float4* Ksrc = (const float4*)(Kc + (size_t)(bb*KV + g)*NBLK*DIM);
    const float4* Vsrc = (const float4*)(Vc + (size_t)(bb*KV + g)*NBLK*DIM);
    for (int i = tid; i < 1024; i += 512){
      int row = i >> 5, seg = i & 31;
      int dst = row*RS + (seg>>3)*QS + (seg&7)*4;
      *(float4*)(sh.b.Ks + dst) = Ksrc[i];
      *(float4*)(sh.b.Vs + dst) = Vsrc[i];
    }
    __syncthreads();

    int qi = tid2 >> 2, c = tid2 & 3;
    int row = bb*SEQ + qb*64 + qi;
    const float* qptr = q + ((size_t)row*QH + g*NH + h)*DIM;

    // scores (full-dim, c owns n = nn*4+c) + lane-local gate
    float sc[8];
#pragma unroll
    for (int nn = 0; nn < 8; ++nn) sc[nn] = 0.f;
    float gp = 0.f;
    for (int qq = 0; qq < 4; ++qq){
      float qv[32];
      const float4* q4 = (const float4*)(qptr + qq*32);
#pragma unroll
      for (int jjj = 0; jjj < 8; ++jjj){
        float4 u = q4[jjj];
        qv[4*jjj+0]=u.x; qv[4*jjj+1]=u.y; qv[4*jjj+2]=u.z; qv[4*jjj+3]=u.w;
      }
#pragma unroll
      for (int d = 0; d < 32; ++d) gp += qv[d]*w_gate[(qq*32+d)*3 + 0];
#pragma unroll
      for (int nn = 0; nn < 8; ++nn){
        int n = nn*4 + c;
        const float4* kr = (const float4*)(sh.b.Ks + n*RS + qq*QS);
        float p = 0.f;
#pragma unroll
        for (int jjj = 0; jjj < 8; ++jjj){
          float4 u = kr[jjj];
          p += qv[4*jjj+0]*u.x + qv[4*jjj+1]*u.y + qv[4*jjj+2]*u.z + qv[4*jjj+3]*u.w;
        }
        sc[nn] += p;
      }
    }
    float g0 = 1.f/(1.f + expf(-(gp + b_gate[0])));

    // softmax across the 4 c-lanes
#pragma unroll
    for (int nn = 0; nn < 8; ++nn) sc[nn] *= SCALE;
    float m = sc[0];
#pragma unroll
    for (int nn = 1; nn < 8; ++nn) m = fmaxf(m, sc[nn]);
    m = fmaxf(m, __shfl_xor(m, 1)); m = fmaxf(m, __shfl_xor(m, 2));
    float l = 0.f;
#pragma unroll
    for (int nn = 0; nn < 8; ++nn){ sc[nn] = expf(sc[nn]-m); l += sc[nn]; }
    l += __shfl_xor(l, 1); l += __shfl_xor(l, 2);
    float inv = 1.f/l;
#pragma unroll
    for (int nn = 0; nn < 8; ++nn) sh.b.Pl[s][qi*PLS + nn*4 + c] = sc[nn]*inv;
    __syncthreads();

    // pooled P (sum over 64 queries)
    if (tid2 < NBLK){
      float ssum = 0.f;
      for (int q2 = 0; q2 < 64; ++q2) ssum += sh.b.Pl[s][q2*PLS + tid2];
      int blk_old = ((bb*KV + g)*NQB + qb)*NH + h;
      pp[(size_t)blk_old*NBLK + tid2] = ssum;
    }

    // PV (c owns dim-quarter; P broadcast from LDS)
    float o[32];
#pragma unroll
    for (int d = 0; d < 32; ++d) o[d] = 0.f;
    for (int n = 0; n < NBLK; ++n){
      float pb = sh.b.Pl[s][qi*PLS + n];
      const float4* vr = (const float4*)(sh.b.Vs + n*RS + c*QS);
#pragma unroll
      for (int jjj = 0; jjj < 8; ++jjj){
        float4 u = vr[jjj];
        o[4*jjj+0] += pb*u.x; o[4*jjj+1] += pb*u.y;
        o[4*jjj+2] += pb*u.z; o[4*jjj+3] += pb*u.w;
      }
    }
    float* op = out + ((size_t)row*QH + g*NH + h)*DIM + c*32;
#pragma unroll
    for (int d = 0; d < 32; ++d) op[d] = g0*o[d];   // overwrite (first branch)
  }
  grid.sync();

  // ======== phase C: role-split topk+slc | win attention (MFMA) =============
  {
    int idx = bm;
    int x = idx & 7, low = idx & 1, u = idx >> 3;
    int bbg = x >> 1;                 // (bb,g): same-bbg blocks share XCD pair
    int j = u*2 + low;                // 0..63
    int role = j >> 5;                // 0 = slc, 1 = win
    int qb = j & 31;
    int bb = bbg >> 1, g = bbg & 1;

    int lane = tid & 63, w = tid >> 6;        // wave 0..7
    int quad = lane >> 4, l15 = lane & 15;
    int h = w & 3, qh2 = w >> 2;              // head, query half
    int xr = (l15 & 7) << 4;                  // read-side XOR (matches prep)

    // top-k (role 0 only; wave 0; lax.top_k tie rule)
    if (role == 0 && tid < 64){
      int n = lane;
      float val = -INFINITY;
      if (n < NBLK){
        const float* p0 = pp + ((size_t)((bb*KV+g)*NQB + qb)*NH)*NBLK + n;
        val = (p0[0] + p0[NBLK]) + (p0[2*NBLK] + p0[3*NBLK]);
      }
      for (int t = 0; t < NTOP; ++t){
        float bv = val; int bi = n;
        for (int mm = 1; mm < 32; mm <<= 1){
          float ov = __shfl_xor(bv, mm);
          int   oi = __shfl_xor(bi, mm);
          if (ov > bv || (ov == bv && oi < bi)){ bv = ov; bi = oi; }
        }
        if (lane == 0) sh.c.idxs[t] = bi;
        if (n == bi) val = -INFINITY;
      }
    }

    // Q fragments (pre-scaled by SCALE*log2e) + exact fp32 gate
    const float* qrow0 = q + ((size_t)(bb*SEQ + qb*64 + qh2*32 + l15)*QH + g*NH + h)*DIM;
    const float* qrow1 = qrow0 + (size_t)16*QH*DIM;
    int gcol = 1 + role;
    bf16x8 qfrag0[4], qfrag1[4];
    float gp0 = 0.f, gp1 = 0.f;
#pragma unroll
    for (int kc = 0; kc < 4; ++kc){
      int d0 = kc*32 + quad*8;
      float4 a0 = *(const float4*)(qrow0 + d0);
      float4 a1 = *(const float4*)(qrow0 + d0 + 4);
      float4 b0 = *(const float4*)(qrow1 + d0);
      float4 b1 = *(const float4*)(qrow1 + d0 + 4);
      float qa[8] = {a0.x,a0.y,a0.z,a0.w,a1.x,a1.y,a1.z,a1.w};
      float qc[8] = {b0.x,b0.y,b0.z,b0.w,b1.x,b1.y,b1.z,b1.w};
#pragma unroll
      for (int jj = 0; jj < 8; ++jj){
        float wg = w_gate[(d0+jj)*3 + gcol];
        gp0 += qa[jj]*wg; gp1 += qc[jj]*wg;
      }
      union { unsigned uu[4]; bf16x8 v8; } t0, t1;
#pragma unroll
      for (int p2 = 0; p2 < 4; ++p2){
        t0.uu[p2] = pkbf(qa[2*p2]*QSC, qa[2*p2+1]*QSC);
        t1.uu[p2] = pkbf(qc[2*p2]*QSC, qc[2*p2+1]*QSC);
      }
      qfrag0[kc] = t0.v8; qfrag1[kc] = t1.v8;
    }
    gp0 += __shfl_xor(gp0,16); gp0 += __shfl_xor(gp0,32);
    gp1 += __shfl_xor(gp1,16); gp1 += __shfl_xor(gp1,32);
    if (quad == 0){
      sh.c.gbuf[w*32 + l15]      = 1.f/(1.f + __expf(-(gp0 + b_gate[gcol])));
      sh.c.gbuf[w*32 + 16 + l15] = 1.f/(1.f + __expf(-(gp1 + b_gate[gcol])));
    }
    __syncthreads();   // publishes gbuf + idxs
    float gl0[4], gl1[4];
#pragma unroll
    for (int r = 0; r < 4; ++r){
      gl0[r] = sh.c.gbuf[w*32 + quad*4 + r];
      gl1[r] = sh.c.gbuf[w*32 + 16 + quad*4 + r];
    }

    const ushort_t* kbase  = Kb + (size_t)bbg*SEQ*DIM;
    const ushort_t* vtbase = VT + (size_t)bbg*DIM*SEQ;

    int kb0 = (qb >= 8) ? (qb - 8) : 0;
    int nph = (role == 0) ? NTOP : (qb - kb0 + 1);
    int qi0 = qh2*32 + l15, qi1 = qi0 + 16;   // lane-local query indices

    float m10 = -INFINITY, l10 = 0.f, m11 = -INFINITY, l11 = 0.f;
    f32x4 oacc0[8], oacc1[8];
    const f32x4 zero4 = {0.f,0.f,0.f,0.f};
#pragma unroll
    for (int dt = 0; dt < 8; ++dt){ oacc0[dt] = zero4; oacc1[dt] = zero4; }

    auto stage = [&](int bufi, int kb_){
      const ushort_t* ksrc = kbase + (size_t)kb_*64*DIM;
#pragma unroll
      for (int jj = 0; jj < 2; ++jj)          // K tile: 1024 16B units
        async16(&sh.c.Ks[bufi][(jj*512 + w*64)*8], ksrc + (size_t)(tid + jj*512)*8);
      const ushort_t* vsrc = vtbase + kb_*64;
#pragma unroll
      for (int jj = 0; jj < 2; ++jj){         // VT tile: [d=128][64]
        int i = tid + jj*512;
        int d = i >> 3, sg = i & 7;
        async16(&sh.c.VTs[bufi][(jj*512 + w*64)*8], vsrc + (size_t)d*SEQ + sg*8);
      }
    };

    stage(0, (role == 0) ? sh.c.idxs[0] : kb0);

    for (int t = 0; t < nph; ++t){
      int cur = t & 1;
      int kb = (role == 0) ? sh.c.idxs[t] : (kb0 + t);
      __syncthreads();                        // buf[cur] resident; cur^1 free
      if (t+1 < nph){
        int kbn = (role == 0) ? sh.c.idxs[t+1] : (kb0 + t + 1);
        stage(cur ^ 1, kbn);                  // flies under this phase
      }
      __builtin_amdgcn_sched_barrier(0);      // pin prefetch issue early

      // QK^T swapped: mfma(K, Q); K A-frags shared across both q-tiles
      f32x4 sacc0[4], sacc1[4];
#pragma unroll
      for (int nt = 0; nt < 4; ++nt){ sacc0[nt] = zero4; sacc1[nt] = zero4; }
      __builtin_amdgcn_s_setprio(1);
#pragma unroll
      for (int kc = 0; kc < 4; ++kc){
#pragma unroll
        for (int nt = 0; nt < 4; ++nt){
          bf16x8 a = *(bf16x8*)((char*)&sh.c.Ks[cur][0] + (nt*16 + l15)*256
                                + ((kc*64 + quad*16) ^ xr));
          sacc0[nt] = __builtin_amdgcn_mfma_f32_16x16x32_bf16(a, qfrag0[kc], sacc0[nt], 0, 0, 0);
          sacc1[nt] = __builtin_amdgcn_mfma_f32_16x16x32_bf16(a, qfrag1[kc], sacc1[nt], 0, 0, 0);
        }
      }
      __builtin_amdgcn_s_setprio(0);

      bool mlow  = (role == 1) && (kb == qb - 8);   // valid: key >= qi
      bool mhigh = (role == 1) && (kb == qb);       // valid: key <= qi
      bool domask = mlow | mhigh;

      auto softmax_qt = [&](f32x4* sc2, float& m1r, float& l1r, int qi_l,
                            bool& skipped) -> float {
        float mx = -INFINITY;
        if (domask){
#pragma unroll
          for (int nt = 0; nt < 4; ++nt)
#pragma unroll
            for (int r = 0; r < 4; ++r){
              int key = nt*16 + quad*4 + r;
              float sv = sc2[nt][r];
              bool valid = (!mlow || key >= qi_l) && (!mhigh || key <= qi_l);
              sv = valid ? sv : -INFINITY;
              sc2[nt][r] = sv;
              mx = fmaxf(mx, sv);
            }
        } else {
#pragma unroll
          for (int nt = 0; nt < 4; ++nt)
#pragma unroll
            for (int r = 0; r < 4; ++r) mx = fmaxf(mx, sc2[nt][r]);
        }
        mx = fmaxf(mx, __shfl_xor(mx, 16));
        mx = fmaxf(mx, __shfl_xor(mx, 32));
        float al = 1.f;
        skipped = __all(mx <= m1r + 8.f);     // defer-max: P bounded by 2^8
        if (!skipped){
          float mn = fmaxf(m1r, mx);
          al = exp2f(m1r - mn);
          m1r = mn;
        }
        float s0 = 0.f;
#pragma unroll
        for (int nt = 0; nt < 4; ++nt)
#pragma unroll
          for (int r = 0; r < 4; ++r){
            float pe = exp2f(sc2[nt][r] - m1r);   // masked -> 0
            sc2[nt][r] = pe;
            s0 += pe;
          }
        s0 += __shfl_xor(s0, 16);
        s0 += __shfl_xor(s0, 32);
        l1r = l1r*al + s0;
        return al;
      };
      bool sk0, sk1;
      float al0 = softmax_qt(sacc0, m10, l10, qi0, sk0);
      float al1 = softmax_qt(sacc1, m11, l11, qi1, sk1);

      // P -> LDS bf16, packed b64 (row = query; wave-private slab)
#pragma unroll
      for (int nt = 0; nt < 4; ++nt){
        uint2 p0, p1;
        p0.x = pkbf(sacc0[nt][0], sacc0[nt][1]);
        p0.y = pkbf(sacc0[nt][2], sacc0[nt][3]);
        p1.x = pkbf(sacc1[nt][0], sacc1[nt][1]);
        p1.y = pkbf(sacc1[nt][2], sacc1[nt][3]);
        *(uint2*)&sh.c.Ps[(w*32 + l15)*VP + nt*16 + quad*4] = p0;
        *(uint2*)&sh.c.Ps[(w*32 + 16 + l15)*VP + nt*16 + quad*4] = p1;
      }

      // O rescale (skipped when defer-max held)
      if (!sk0){
        float ar[4];
#pragma unroll
        for (int r = 0; r < 4; ++r) ar[r] = __shfl(al0, quad*4 + r);
#pragma unroll
        for (int dt = 0; dt < 8; ++dt)
#pragma unroll
          for (int r = 0; r < 4; ++r) oacc0[dt][r] *= ar[r];
      }
      if (!sk1){
        float ar[4];
#pragma unroll
        for (int r = 0; r < 4; ++r) ar[r] = __shfl(al1, quad*4 + r);
#pragma unroll
        for (int dt = 0; dt < 8; ++dt)
#pragma unroll
          for (int r = 0; r < 4; ++r) oacc1[dt][r] *= ar[r];
      }

      // PV: V B-frags shared across both q-tiles
#pragma unroll
      for (int kc2 = 0; kc2 < 2; ++kc2){
        bf16x8 pa0 = *(bf16x8*)&sh.c.Ps[(w*32 + l15)*VP + kc2*32 + quad*8];
        bf16x8 pa1 = *(bf16x8*)&sh.c.Ps[(w*32 + 16 + l15)*VP + kc2*32 + quad*8];
        __builtin_amdgcn_s_setprio(1);
#pragma unroll
        for (int dt = 0; dt < 8; ++dt){
          bf16x8 vb8 = *(bf16x8*)((char*)&sh.c.VTs[cur][0] + (dt*16 + l15)*128
                                  + ((kc2*64 + quad*16) ^ xr));
          oacc0[dt] = __builtin_amdgcn_mfma_f32_16x16x32_bf16(pa0, vb8, oacc0[dt], 0, 0, 0);
          oacc1[dt] = __builtin_amdgcn_mfma_f32_16x16x32_bf16(pa1, vb8, oacc1[dt], 0, 0, 0);
        }
        __builtin_amdgcn_s_setprio(0);
      }
    }

    // epilogue: race-free plain stores
    float lr0[4], lr1[4];
#pragma unroll
    for (int r = 0; r < 4; ++r){
      lr0[r] = __shfl(l10, quad*4 + r);
      lr1[r] = __shfl(l11, quad*4 + r);
    }
#pragma unroll
    for (int r = 0; r < 4; ++r){
      float s20 = gl0[r] / lr0[r];
      float s21 = gl1[r] / lr1[r];
      size_t ob0 = ((size_t)(bb*SEQ + qb*64 + qh2*32 + quad*4 + r)*QH + g*NH + h)*DIM + l15;
      size_t ob1 = ob0 + (size_t)16*QH*DIM;
      if (role == 0){
        float* op0 = slcbuf + ob0;            // unique writer; full coverage
        float* op1 = slcbuf + ob1;
#pragma unroll
        for (int dt = 0; dt < 8; ++dt){
          op0[dt*16] = s20 * oacc0[dt][r];
          op1[dt*16] = s21 * oacc1[dt][r];
        }
      } else {
        float* op0 = out + ob0;               // unique writer; cmp already done
        float* op1 = out + ob1;
#pragma unroll
        for (int dt = 0; dt < 8; ++dt){
          op0[dt*16] += s20 * oacc0[dt][r];
          op1[dt*16] += s21 * oacc1[dt][r];
        }
      }
    }
  }
  grid.sync();

  // ======== phase D: merge (out += slcbuf) ==================================
  {
    const float4* sb = (const float4*)slcbuf;
    float4* ob = (float4*)out;
#pragma unroll
    for (int jj = 0; jj < 8; ++jj){
      int i = bm*512 + tid + jj*131072;       // 1,048,576 float4s total
      float4 a4 = sb[i];
      float4 b4 = ob[i];
      b4.x += a4.x; b4.y += a4.y; b4.z += a4.z; b4.w += a4.w;
      ob[i] = b4;
    }
  }
}

// ==================== fallback 4-kernel path (r13) ==========================
__global__ __launch_bounds__(256) void prep_k(
    const float* __restrict__ k, const float* __restrict__ v,
    const float* __restrict__ w_k, const float* __restrict__ b_k,
    const float* __restrict__ w_v, const float* __restrict__ b_v,
    ushort_t* __restrict__ Kb, ushort_t* __restrict__ VT,
    float* __restrict__ Kc, float* __restrict__ Vc)
{
  int blk = blockIdx.x;
  int db = blk & 1, rb = (blk >> 1) & 31, bbg = blk >> 6;
  int bb = bbg >> 1, g = bbg & 1;
  int tid = threadIdx.x;
  __shared__ ushort_t T[64*VP];
  __shared__ float wks[64], wvs[64];
  __shared__ float accK[16][64], accV[16][64];

  if (tid < 64){ wks[tid] = w_k[tid]; wvs[tid] = w_v[tid]; }
  __syncthreads();

  float4 sk = {0,0,0,0}, sv = {0,0,0,0};
  for (int jj = 0; jj < 4; ++jj){
    int i = tid + jj*256;
    int r = i >> 4, ds = i & 15;
    size_t src = ((size_t)(bb*SEQ + rb*64 + r)*KV + g)*DIM + db*64 + ds*4;
    float4 kx = *(const float4*)(k + src);
    float4 vx = *(const float4*)(v + src);
    uint2 kk; kk.x = pkbf(kx.x,kx.y); kk.y = pkbf(kx.z,kx.w);
    size_t rowb = ((size_t)bbg*SEQ + rb*64 + r)*DIM*2;
    int swz = (db*128 + ds*8) ^ ((r & 7) << 4);
    *(uint2*)((char*)Kb + rowb + swz) = kk;
    unsigned v01 = pkbf(vx.x,vx.y), v23 = pkbf(vx.z,vx.w);
    T[(ds*4+0)*VP + r] = (ushort_t)(v01 & 0xffffu);
    T[(ds*4+1)*VP + r] = (ushort_t)(v01 >> 16);
    T[(ds*4+2)*VP + r] = (ushort_t)(v23 & 0xffffu);
    T[(ds*4+3)*VP + r] = (ushort_t)(v23 >> 16);
    float a = wks[r], b = wvs[r];
    sk.x += a*kx.x; sk.y += a*kx.y; sk.z += a*kx.z; sk.w += a*kx.w;
    sv.x += b*vx.x; sv.y += b*vx.y; sv.z += b*vx.z; sv.w += b*vx.w;
  }
  *(float4*)&accK[tid>>4][(tid&15)*4] = sk;
  *(float4*)&accV[tid>>4][(tid&15)*4] = sv;
  __syncthreads();

  for (int jj = 0; jj < 4; ++jj){
    int i = tid + jj*256;
    int d = i >> 4, seg = i & 15;
    uint2 u = *(uint2*)&T[d*VP + seg*4];
    size_t rowb = ((size_t)bbg*DIM + db*64 + d)*SEQ*2;
    int swz = (seg*8) ^ ((d & 7) << 4);
    *(uint2*)((char*)VT + rowb + rb*128 + swz) = u;
  }

  size_t obase = ((size_t)(bbg*NBLK + rb))*DIM + db*64;
  if (tid < 64){
    float s = 0.f;
#pragma unroll
    for (int i = 0; i < 16; ++i) s += accK[i][tid];
    Kc[obase + tid] = s + b_k[0];
  } else if (tid < 128){
    int d = tid - 64;
    float s = 0.f;
#pragma unroll
    for (int i = 0; i < 16; ++i) s += accV[i][d];
    Vc[obase + d] = s + b_v[0];
  }
}

__global__ __launch_bounds__(256) void cmp_attn_k(
    const float* __restrict__ q, const float* __restrict__ Kc,
    const float* __restrict__ Vc,
    const float* __restrict__ w_gate, const float* __restrict__ b_gate,
    float* __restrict__ pooled_part, float* __restrict__ out)
{
  int blk = blockIdx.x;
  int h  = blk & 3;
  int qb = (blk >> 2) & (NQB-1);
  int g  = (blk >> 7) & 1;
  int bb = blk >> 8;
  int tid = threadIdx.x;
  int qi = tid >> 2, c = tid & 3;

  __shared__ float Ks[32*RS];
  __shared__ float Vs[32*RS];
  __shared__ float Pl[64*PLS];

  const float4* Ksrc = (const float4*)(Kc + (size_t)(bb*KV + g) * NBLK * DIM);
  const float4* Vsrc = (const float4*)(Vc + (size_t)(bb*KV + g) * NBLK * DIM);
  for (int i = tid; i < 1024; i += 256){
    int row = i >> 5, seg = i & 31;
    int dst = row*RS + (seg>>3)*QS + (seg&7)*4;
    ((float4*)(Ks+dst))[0] = Ksrc[i];
    ((float4*)(Vs+dst))[0] = Vsrc[i];
  }
  __syncthreads();

  int row = bb*SEQ + qb*64 + qi;
  const float* qptr = q + ((size_t)row*QH + g*NH + h)*DIM;

  float sc[8];
#pragma unroll
  for (int nn = 0; nn < 8; ++nn) sc[nn] = 0.f;
  float gp = 0.f;
  for (int qq = 0; qq < 4; ++qq){
    float qv[32];
    const float4* q4 = (const float4*)(qptr + qq*32);
#pragma unroll
    for (int j = 0; j < 8; ++j){
      float4 u = q4[j];
      qv[4*j+0]=u.x; qv[4*j+1]=u.y; qv[4*j+2]=u.z; qv[4*j+3]=u.w;
    }
#pragma unroll
    for (int d = 0; d < 32; ++d) gp += qv[d]*w_gate[(qq*32+d)*3 + 0];
#pragma unroll
    for (int nn = 0; nn < 8; ++nn){
      int n = nn*4 + c;
      const float4* kr = (const float4*)(Ks + n*RS + qq*QS);
      float p = 0.f;
#pragma unroll
      for (int j = 0; j < 8; ++j){
        float4 u = kr[j];
        p += qv[4*j+0]*u.x + qv[4*j+1]*u.y + qv[4*j+2]*u.z + qv[4*j+3]*u.w;
      }
      sc[nn] += p;
    }
  }
  float g0 = 1.f/(1.f + expf(-(gp + b_gate[0])));

#pragma unroll
  for (int nn = 0; nn < 8; ++nn) sc[nn] *= SCALE;
  float m = sc[0];
#pragma unroll
  for (int nn = 1; nn < 8; ++nn) m = fmaxf(m, sc[nn]);
  m = fmaxf(m, __shfl_xor(m, 1)); m = fmaxf(m, __shfl_xor(m, 2));
  float l = 0.f;
#pragma unroll
  for (int nn = 0; nn < 8; ++nn){ sc[nn] = expf(sc[nn]-m); l += sc[nn]; }
  l += __shfl_xor(l, 1); l += __shfl_xor(l, 2);
  float inv = 1.f/l;
#pragma unroll
  for (int nn = 0; nn < 8; ++nn) Pl[qi*PLS + nn*4 + c] = sc[nn]*inv;
  __syncthreads();

  if (tid < NBLK){
    float s = 0.f;
    for (int q2 = 0; q2 < 64; ++q2) s += Pl[q2*PLS + tid];
    pooled_part[(size_t)blk*NBLK + tid] = s;
  }

  float o[32];
#pragma unroll
  for (int d = 0; d < 32; ++d) o[d] = 0.f;
  for (int n = 0; n < NBLK; ++n){
    float pb = Pl[qi*PLS + n];
    const float4* vr = (const float4*)(Vs + n*RS + c*QS);
#pragma unroll
    for (int j = 0; j < 8; ++j){
      float4 u = vr[j];
      o[4*j+0] += pb*u.x; o[4*j+1] += pb*u.y;
      o[4*j+2] += pb*u.z; o[4*j+3] += pb*u.w;
    }
  }
  float* op = out + ((size_t)row*QH + g*NH + h)*DIM + c*32;
#pragma unroll
  for (int d = 0; d < 32; ++d) op[d] = g0*o[d];
}

__global__ __launch_bounds__(512, 2) void attn_k(
    const float* __restrict__ q, const ushort_t* __restrict__ Kb,
    const ushort_t* __restrict__ VT, const float* __restrict__ pp,
    const float* __restrict__ w_gate, const float* __restrict__ b_gate,
    float* __restrict__ slcbuf, float* __restrict__ out)
{
  int idx = blockIdx.x;
  int x = idx & 7, low = idx & 1, u = idx >> 3;
  int bbg = x >> 1;
  int j = u*2 + low;
  int role = j >> 5;
  int qb = j & 31;
  int bb = bbg >> 1, g = bbg & 1;

  int tid = threadIdx.x;
  int lane = tid & 63, w = tid >> 6;
  int quad = lane >> 4, l15 = lane & 15;
  int h = w & 3, qh2 = w >> 2;
  int xr = (l15 & 7) << 4;

  __shared__ ushort_t Ks[2][64*128];
  __shared__ ushort_t VTs[2][128*64];
  __shared__ ushort_t Ps[256*VP];
  __shared__ float gbuf[256];
  __shared__ int   idxs[NTOP];

  if (role == 0 && tid < 64){
    int n = lane;
    float val = -INFINITY;
    if (n < NBLK){
      const float* p0 = pp + ((size_t)((bb*KV+g)*NQB + qb)*NH)*NBLK + n;
      val = (p0[0] + p0[NBLK]) + (p0[2*NBLK] + p0[3*NBLK]);
    }
    for (int t = 0; t < NTOP; ++t){
      float bv = val; int bi = n;
      for (int mm = 1; mm < 32; mm <<= 1){
        float ov = __shfl_xor(bv, mm);
        int   oi = __shfl_xor(bi, mm);
        if (ov > bv || (ov == bv && oi < bi)){ bv = ov; bi = oi; }
      }
      if (lane == 0) idxs[t] = bi;
      if (n == bi) val = -INFINITY;
    }
  }

  const float* qrow0 = q + ((size_t)(bb*SEQ + qb*64 + qh2*32 + l15)*QH + g*NH + h)*DIM;
  const float* qrow1 = qrow0 + (size_t)16*QH*DIM;
  int gcol = 1 + role;
  bf16x8 qfrag0[4], qfrag1[4];
  float gp0 = 0.f, gp1 = 0.f;
#pragma unroll
  for (int kc = 0; kc < 4; ++kc){
    int d0 = kc*32 + quad*8;
    float4 a0 = *(const float4*)(qrow0 + d0);
    float4 a1 = *(const float4*)(qrow0 + d0 + 4);
    float4 b0 = *(const float4*)(qrow1 + d0);
    float4 b1 = *(const float4*)(qrow1 + d0 + 4);
    float qa[8] = {a0.x,a0.y,a0.z,a0.w,a1.x,a1.y,a1.z,a1.w};
    float qc[8] = {b0.x,b0.y,b0.z,b0.w,b1.x,b1.y,b1.z,b1.w};
#pragma unroll
    for (int jj = 0; jj < 8; ++jj){
      float wg = w_gate[(d0+jj)*3 + gcol];
      gp0 += qa[jj]*wg; gp1 += qc[jj]*wg;
    }
    union { unsigned uu[4]; bf16x8 v8; } t0, t1;
#pragma unroll
    for (int p2 = 0; p2 < 4; ++p2){
      t0.uu[p2] = pkbf(qa[2*p2]*QSC, qa[2*p2+1]*QSC);
      t1.uu[p2] = pkbf(qc[2*p2]*QSC, qc[2*p2+1]*QSC);
    }
    qfrag0[kc] = t0.v8; qfrag1[kc] = t1.v8;
  }
  gp0 += __shfl_xor(gp0,16); gp0 += __shfl_xor(gp0,32);
  gp1 += __shfl_xor(gp1,16); gp1 += __shfl_xor(gp1,32);
  if (quad == 0){
    gbuf[w*32 + l15]      = 1.f/(1.f + __expf(-(gp0 + b_gate[gcol])));
    gbuf[w*32 + 16 + l15] = 1.f/(1.f + __expf(-(gp1 + b_gate[gcol])));
  }
  __syncthreads();
  float gl0[4], gl1[4];
#pragma unroll
  for (int r = 0; r < 4; ++r){
    gl0[r] = gbuf[w*32 + quad*4 + r];
    gl1[r] = gbuf[w*32 + 16 + quad*4 + r];
  }

  const ushort_t* kbase  = Kb + (size_t)bbg*SEQ*DIM;
  const ushort_t* vtbase = VT + (size_t)bbg*DIM*SEQ;

  int kb0 = (qb >= 8) ? (qb - 8) : 0;
  int nph = (role == 0) ? NTOP : (qb - kb0 + 1);
  int qi0 = qh2*32 + l15, qi1 = qi0 + 16;

  float m10 = -INFINITY, l10 = 0.f, m11 = -INFINITY, l11 = 0.f;
  f32x4 oacc0[8], oacc1[8];
  const f32x4 zero4 = {0.f,0.f,0.f,0.f};
#pragma unroll
  for (int dt = 0; dt < 8; ++dt){ oacc0[dt] = zero4; oacc1[dt] = zero4; }

  auto stage = [&](int bufi, int kb_){
    const ushort_t* ksrc = kbase + (size_t)kb_*64*DIM;
#pragma unroll
    for (int jj = 0; jj < 2; ++jj)
      async16(&Ks[bufi][(jj*512 + w*64)*8], ksrc + (size_t)(tid + jj*512)*8);
    const ushort_t* vsrc = vtbase + kb_*64;
#pragma unroll
    for (int jj = 0; jj < 2; ++jj){
      int i = tid + jj*512;
      int d = i >> 3, sg = i & 7;
      async16(&VTs[bufi][(jj*512 + w*64)*8], vsrc + (size_t)d*SEQ + sg*8);
    }
  };

  stage(0, (role == 0) ? idxs[0] : kb0);

  for (int t = 0; t < nph; ++t){
    int cur = t & 1;
    int kb = (role == 0) ? idxs[t] : (kb0 + t);
    __syncthreads();
    if (t+1 < nph){
      int kbn = (role == 0) ? idxs[t+1] : (kb0 + t + 1);
      stage(cur ^ 1, kbn);
    }
    __builtin_amdgcn_sched_barrier(0);

    f32x4 sacc0[4], sacc1[4];
#pragma unroll
    for (int nt = 0; nt < 4; ++nt){ sacc0[nt] = zero4; sacc1[nt] = zero4; }
    __builtin_amdgcn_s_setprio(1);
#pragma unroll
    for (int kc = 0; kc < 4; ++kc){
#pragma unroll
      for (int nt = 0; nt < 4; ++nt){
        bf16x8 a = *(bf16x8*)((char*)&Ks[cur][0] + (nt*16 + l15)*256
                              + ((kc*64 + quad*16) ^ xr));
        sacc0[nt] = __builtin_amdgcn_mfma_f32_16x16x32_bf16(a, qfrag0[kc], sacc0[nt], 0, 0, 0);
        sacc1[nt] = __builtin_amdgcn_mfma_f32_16x16x32_bf16(a, qfrag1[kc], sacc1[nt], 0, 0, 0);
      }
    }
    __builtin_amdgcn_s_setprio(0);

    bool mlow  = (role == 1) && (kb == qb - 8);
    bool mhigh = (role == 1) && (kb == qb);
    bool domask = mlow | mhigh;

    auto softmax_qt = [&](f32x4* sc, float& m1r, float& l1r, int qi_l,
                          bool& skipped) -> float {
      float mx = -INFINITY;
      if (domask){
#pragma unroll
        for (int nt = 0; nt < 4; ++nt)
#pragma unroll
          for (int r = 0; r < 4; ++r){
            int key = nt*16 + quad*4 + r;
            float sv = sc[nt][r];
            bool valid = (!mlow || key >= qi_l) && (!mhigh || key <= qi_l);
            sv = valid ? sv : -INFINITY;
            sc[nt][r] = sv;
            mx = fmaxf(mx, sv);
          }
      } else {
#pragma unroll
        for (int nt = 0; nt < 4; ++nt)
#pragma unroll
          for (int r = 0; r < 4; ++r) mx = fmaxf(mx, sc[nt][r]);
      }
      mx = fmaxf(mx, __shfl_xor(mx, 16));
      mx = fmaxf(mx, __shfl_xor(mx, 32));
      float al = 1.f;
      skipped = __all(mx <= m1r + 8.f);
      if (!skipped){
        float mn = fmaxf(m1r, mx);
        al = exp2f(m1r - mn);
        m1r = mn;
      }
      float s0 = 0.f;
#pragma unroll
      for (int nt = 0; nt < 4; ++nt)
#pragma unroll
        for (int r = 0; r < 4; ++r){
          float pe = exp2f(sc[nt][r] - m1r);
          sc[nt][r] = pe;
          s0 += pe;
        }
      s0 += __shfl_xor(s0, 16);
      s0 += __shfl_xor(s0, 32);
      l1r = l1r*al + s0;
      return al;
    };
    bool sk0, sk1;
    float al0 = softmax_qt(sacc0, m10, l10, qi0, sk0);
    float al1 = softmax_qt(sacc1, m11, l11, qi1, sk1);

#pragma unroll
    for (int nt = 0; nt < 4; ++nt){
      uint2 p0, p1;
      p0.x = pkbf(sacc0[nt][0], sacc0[nt][1]);
      p0.y = pkbf(sacc0[nt][2], sacc0[nt][3]);
      p1.x = pkbf(sacc1[nt][0], sacc1[nt][1]);
      p1.y = pkbf(sacc1[nt][2], sacc1[nt][3]);
      *(uint2*)&Ps[(w*32 + l15)*VP + nt*16 + quad*4] = p0;
      *(uint2*)&Ps[(w*32 + 16 + l15)*VP + nt*16 + quad*4] = p1;
    }

    if (!sk0){
      float ar[4];
#pragma unroll
      for (int r = 0; r < 4; ++r) ar[r] = __shfl(al0, quad*4 + r);
#pragma unroll
      for (int dt = 0; dt < 8; ++dt)
#pragma unroll
        for (int r = 0; r < 4; ++r) oacc0[dt][r] *= ar[r];
    }
    if (!sk1){
      float ar[4];
#pragma unroll
      for (int r = 0; r < 4; ++r) ar[r] = __shfl(al1, quad*4 + r);
#pragma unroll
      for (int dt = 0; dt < 8; ++dt)
#pragma unroll
        for (int r = 0; r < 4; ++r) oacc1[dt][r] *= ar[r];
    }

#pragma unroll
    for (int kc2 = 0; kc2 < 2; ++kc2){
      bf16x8 pa0 = *(bf16x8*)&Ps[(w*32 + l15)*VP + kc2*32 + quad*8];
      bf16x8 pa1 = *(bf16x8*)&Ps[(w*32 + 16 + l15)*VP + kc2*32 + quad*8];
      __builtin_amdgcn_s_setprio(1);
#pragma unroll
      for (int dt = 0; dt < 8; ++dt){
        bf16x8 vb8 = *(bf16x8*)((char*)&VTs[cur][0] + (dt*16 + l15)*128
                                + ((kc2*64 + quad*16) ^ xr));
        oacc0[dt] = __builtin_amdgcn_mfma_f32_16x16x32_bf16(pa0, vb8, oacc0[dt], 0, 0, 0);
        oacc1[dt] = __builtin_amdgcn_mfma_f32_16x16x32_bf16(pa1, vb8, oacc1[dt], 0, 0, 0);
      }
      __builtin_amdgcn_s_setprio(0);
    }
  }

  float lr0[4], lr1[4];
#pragma unroll
  for (int r = 0; r < 4; ++r){
    lr0[r] = __shfl(l10, quad*4 + r);
    lr1[r] = __shfl(l11, quad*4 + r);
  }
#pragma unroll
  for (int r = 0; r < 4; ++r){
    float s20 = gl0[r] / lr0[r];
    float s21 = gl1[r] / lr1[r];
    size_t ob0 = ((size_t)(bb*SEQ + qb*64 + qh2*32 + quad*4 + r)*QH + g*NH + h)*DIM + l15;
    size_t ob1 = ob0 + (size_t)16*QH*DIM;
    if (role == 0){
      float* op0 = slcbuf + ob0;
      float* op1 = slcbuf + ob1;
#pragma unroll
      for (int dt = 0; dt < 8; ++dt){
        op0[dt*16] = s20 * oacc0[dt][r];
        op1[dt*16] = s21 * oacc1[dt][r];
      }
    } else {
      float* op0 = out + ob0;
      float* op1 = out + ob1;
#pragma unroll
      for (int dt = 0; dt < 8; ++dt){
        op0[dt*16] += s20 * oacc0[dt][r];
        op1[dt*16] += s21 * oacc1[dt][r];
      }
    }
  }
}

__global__ __launch_bounds__(256) void merge_k(const float* __restrict__ slcbuf,
                                               float* __restrict__ out){
  int i = blockIdx.x * 256 + threadIdx.x;
  float4 a = ((const float4*)slcbuf)[i];
  float4 b = ((float4*)out)[i];
  b.x += a.x; b.y += a.y; b.z += a.z; b.w += a.w;
  ((float4*)out)[i] = b;
}

extern "C" void kernel_launch(void* const* d_in, const int* in_sizes, int n_in,
                              void* d_out, int out_size, void* d_ws, size_t ws_size,
                              hipStream_t stream) {
  const float* q      = (const float*)d_in[0];
  const float* k      = (const float*)d_in[1];
  const float* v      = (const float*)d_in[2];
  const float* w_k    = (const float*)d_in[3];
  const float* b_k    = (const float*)d_in[4];
  const float* w_v    = (const float*)d_in[5];
  const float* b_v    = (const float*)d_in[6];
  const float* w_gate = (const float*)d_in[7];
  const float* b_gate = (const float*)d_in[8];
  float* out = (float*)d_out;

  float* ws     = (float*)d_ws;
  float* Kc     = ws;                        // 16384 f32
  float* Vc     = ws + 16384;                // 16384 f32
  float* pp     = ws + 32768;                // 512*32 f32
  float* slcbuf = ws + 49152;                // 4.19M f32 (16.8 MB)
  ushort_t* Kb  = (ushort_t*)(ws + 4243456); // 4*2048*128 bf16 (2 MB)
  ushort_t* VT  = Kb + 1048576;              // 4*128*2048 bf16 (2 MB)

  void* args[] = {
    (void*)&q, (void*)&k, (void*)&v, (void*)&w_k, (void*)&b_k,
    (void*)&w_v, (void*)&b_v, (void*)&w_gate, (void*)&b_gate,
    (void*)&Kc, (void*)&Vc, (void*)&pp, (void*)&slcbuf,
    (void*)&Kb, (void*)&VT, (void*)&out };

  hipError_t e = hipLaunchCooperativeKernel((const void*)nsa_mono,
                                            dim3(256), dim3(512),
                                            args, 0, stream);
  if (e != hipSuccess){
    // fallback: 4-kernel path (r13)
    prep_k    <<<256, 256, 0, stream>>>(k, v, w_k, b_k, w_v, b_v, Kb, VT, Kc, Vc);
    cmp_attn_k<<<NB*KV*NQB*NH, 256, 0, stream>>>(q, Kc, Vc, w_gate, b_gate, pp, out);
    attn_k    <<<256, 512, 0, stream>>>(q, Kb, VT, pp, w_gate, b_gate, slcbuf, out);
    merge_k   <<<4096, 256, 0, stream>>>(slcbuf, out);
  }
}

// Round 5
// 166.340 us; speedup vs baseline: 1.9195x; 1.9195x over previous
//
#include <hip/hip_runtime.h>
#include <hip/hip_bf16.h>

// NSA forward, MI355X round 15. All inputs fp32, output fp32.
// r13 with cmp_attn_k DELETED: the compressed-attention branch is folded into
// attn_k's role-0 blocks as MFMA phases (hi/lo bf16 split for ~fp32 score
// accuracy -> top-k-safe). pooled-P + top-k are block-local (all 4 heads in
// block); pp global roundtrip removed. cmp P kept in regs across the slc
// loop, PV'd after it (oacc pre-scaled by g_slc/l_slc, then += g0*Pn*Vc).
// role1 now OVERWRITES out (cmp no longer pre-writes); merge adds slcbuf.
// 3 kernels: prep (bf16 swizzle + compression), attn (cmp+slc | win), merge.
// Shapes: S=4096, seqlen=2048, qh=8, kvh=2, dim=128, blk=64, TOPK=16,
// window=(512,0).

#define SEQ   2048
#define NB    2
#define KV    2
#define NH    4
#define QH    8
#define DIM   128
#define NBLK  32
#define NQB   32
#define NTOP  16
#define SCALE 0.08838834764831845f   // 128^-0.5
#define QSC   0.12751831795244785f   // SCALE * log2(e)
#define VP    72                     // P/prep-T LDS row stride (bf16): pad 8
#define VCS   40                     // VcT LDS row stride (bf16): 32 + pad 8

typedef unsigned short ushort_t;
using bf16x8 = __attribute__((ext_vector_type(8))) short;
using f32x4  = __attribute__((ext_vector_type(4))) float;

__device__ __forceinline__ unsigned pkbf(float a, float b){
  union { __hip_bfloat162 h; unsigned u; } cv;
  cv.h = __float22bfloat162_rn(make_float2(a, b));
  return cv.u;
}
__device__ __forceinline__ ushort_t b16(float f){
  union { float f; unsigned i; } x; x.f = f;
  unsigned r = x.i + 0x7fffu + ((x.i >> 16) & 1u);   // RNE
  return (ushort_t)(r >> 16);
}
__device__ __forceinline__ float fb(ushort_t h){
  union { unsigned i; float f; } x; x.i = ((unsigned)h) << 16;
  return x.f;
}

// async 16B direct-to-LDS copy (per-lane global src, wave-uniform LDS base)
__device__ __forceinline__ void async16(ushort_t* l, const ushort_t* g){
  __builtin_amdgcn_global_load_lds(
      (const __attribute__((address_space(1))) unsigned int*)(size_t)g,
      (__attribute__((address_space(3))) unsigned int*)(size_t)l,
      16, 0, 0);
}

// -------- kernel 0: K/V bf16 preprocessing + block compression (fused) ------
// Kb row-major [bbg][row][128] bf16, each 256B row stored XOR-swizzled:
// byte ^= (row&7)<<4.  VT transposed [bbg][d][SEQ] bf16; within each 128B
// (64-seq) tile: byte ^= (d&7)<<4.  Also computes Kc/Vc (w_k/w_v-weighted
// row sums per 64-block) from the same float4 loads.
__global__ __launch_bounds__(256) void prep_k(
    const float* __restrict__ k, const float* __restrict__ v,
    const float* __restrict__ w_k, const float* __restrict__ b_k,
    const float* __restrict__ w_v, const float* __restrict__ b_v,
    ushort_t* __restrict__ Kb, ushort_t* __restrict__ VT,
    float* __restrict__ Kc, float* __restrict__ Vc)
{
  int blk = blockIdx.x;
  int db = blk & 1, rb = (blk >> 1) & 31, bbg = blk >> 6;
  int bb = bbg >> 1, g = bbg & 1;
  int tid = threadIdx.x;
  __shared__ ushort_t T[64*VP];    // [d 0..63][key 0..63], pad 8
  __shared__ float wks[64], wvs[64];
  __shared__ float accK[16][64], accV[16][64];

  if (tid < 64){ wks[tid] = w_k[tid]; wvs[tid] = w_v[tid]; }
  __syncthreads();

  float4 sk = {0,0,0,0}, sv = {0,0,0,0};
  for (int jj = 0; jj < 4; ++jj){
    int i = tid + jj*256;                 // 1024 float4 units (64 rows x 16)
    int r = i >> 4, ds = i & 15;
    size_t src = ((size_t)(bb*SEQ + rb*64 + r)*KV + g)*DIM + db*64 + ds*4;
    float4 kx = *(const float4*)(k + src);
    float4 vx = *(const float4*)(v + src);
    uint2 kk; kk.x = pkbf(kx.x,kx.y); kk.y = pkbf(kx.z,kx.w);
    size_t rowb = ((size_t)bbg*SEQ + rb*64 + r)*DIM*2;        // row base bytes
    int swz = (db*128 + ds*8) ^ ((r & 7) << 4);               // within-row
    *(uint2*)((char*)Kb + rowb + swz) = kk;
    unsigned v01 = pkbf(vx.x,vx.y), v23 = pkbf(vx.z,vx.w);
    T[(ds*4+0)*VP + r] = (ushort_t)(v01 & 0xffffu);
    T[(ds*4+1)*VP + r] = (ushort_t)(v01 >> 16);
    T[(ds*4+2)*VP + r] = (ushort_t)(v23 & 0xffffu);
    T[(ds*4+3)*VP + r] = (ushort_t)(v23 >> 16);
    float a = wks[r], b = wvs[r];
    sk.x += a*kx.x; sk.y += a*kx.y; sk.z += a*kx.z; sk.w += a*kx.w;
    sv.x += b*vx.x; sv.y += b*vx.y; sv.z += b*vx.z; sv.w += b*vx.w;
  }
  *(float4*)&accK[tid>>4][(tid&15)*4] = sk;
  *(float4*)&accV[tid>>4][(tid&15)*4] = sv;
  __syncthreads();

  for (int jj = 0; jj < 4; ++jj){
    int i = tid + jj*256;                 // 1024 8B units (64 d x 16)
    int d = i >> 4, seg = i & 15;
    uint2 u = *(uint2*)&T[d*VP + seg*4];
    size_t rowb = ((size_t)bbg*DIM + db*64 + d)*SEQ*2;        // d-row bytes
    int swz = (seg*8) ^ ((d & 7) << 4);                       // within 128B tile
    *(uint2*)((char*)VT + rowb + rb*128 + swz) = u;
  }

  size_t obase = ((size_t)(bbg*NBLK + rb))*DIM + db*64;
  if (tid < 64){
    float s = 0.f;
#pragma unroll
    for (int i = 0; i < 16; ++i) s += accK[i][tid];
    Kc[obase + tid] = s + b_k[0];
  } else if (tid < 128){
    int d = tid - 64;
    float s = 0.f;
#pragma unroll
    for (int i = 0; i < 16; ++i) s += accV[i][d];
    Vc[obase + d] = s + b_v[0];
  }
}

// ---- kernel 1: role-split (cmp+topk+slc) | win attention (MFMA) ------------
// grid 256, 512 threads. block = (bbg, qb, role); wave w: head w&3, qhalf w>>2.
// Swapped QK^T: C[col=l15=query][row=quad*4+r=key] -> lane-local softmax.
// role0 additionally runs the compressed branch: hi/lo bf16 MFMA for ~fp32
// scores -> exact-enough pooled P -> block-local top-k; cmp P held in regs
// across the slc loop; cmp PV after oacc pre-scale.
// Layouts (m89/m91/m120): A[m=lane&15][k=quad*8+j], B[k=quad*8+j][n=lane&15],
// C[col=lane&15,row=quad*4+r]
__global__ __launch_bounds__(512, 2) void attn_k(
    const float* __restrict__ q, const ushort_t* __restrict__ Kb,
    const ushort_t* __restrict__ VT,
    const float* __restrict__ Kc, const float* __restrict__ Vc,
    const float* __restrict__ w_gate, const float* __restrict__ b_gate,
    float* __restrict__ slcbuf, float* __restrict__ out)
{
  int idx = blockIdx.x;             // 256 blocks
  int x = idx & 7, low = idx & 1, u = idx >> 3;
  int bbg = x >> 1;                 // (bb,g): same-bbg blocks share XCD pair
  int j = u*2 + low;                // 0..63
  int role = j >> 5;                // 0 = cmp+slc, 1 = win
  int qb = j & 31;
  int bb = bbg >> 1, g = bbg & 1;

  int tid = threadIdx.x;
  int lane = tid & 63, w = tid >> 6;        // wave 0..7
  int quad = lane >> 4, l15 = lane & 15;
  int h = w & 3, qh2 = w >> 2;              // head, query half
  int xr = (l15 & 7) << 4;                  // read-side XOR (matches prep_k)

  __shared__ ushort_t Ks[2][64*128];    // 32 KB (double buffer, linear+swz)
  __shared__ ushort_t VTs[2][128*64];   // 32 KB
  __shared__ ushort_t Ps[256*VP];       // 36 KB (per-wave 32-row slabs)
  __shared__ ushort_t VcTh[128*VCS];    // 10 KB cmp V^T hi
  __shared__ ushort_t VcTl[128*VCS];    // 10 KB cmp V^T lo
  __shared__ float pw[8][NBLK];         //  1 KB pooled partials per wave
  __shared__ float gbuf[256];
  __shared__ int   idxs[NTOP];

  // ---- role0: stage cmp tiles (Kc hi/lo -> Ks[0] rows 0-31/32-63; Vc -> VcT)
  if (role == 0){
    {
      int key = tid >> 4, dq = tid & 15;          // 32 keys x 16 dim-octets
      const float* kcs = Kc + ((size_t)bbg*NBLK + key)*DIM + dq*8;
      float4 f0 = *(const float4*)kcs, f1 = *(const float4*)(kcs + 4);
      float fe[8] = {f0.x,f0.y,f0.z,f0.w,f1.x,f1.y,f1.z,f1.w};
      union { ushort_t u[8]; uint4 v; } hi, lo;
#pragma unroll
      for (int e = 0; e < 8; ++e){
        ushort_t hh = b16(fe[e]);
        hi.u[e] = hh; lo.u[e] = b16(fe[e] - fb(hh));
      }
      int off = (dq*16) ^ ((key & 7) << 4);
      *(uint4*)((char*)&Ks[0][0] + key*256 + off) = hi.v;
      *(uint4*)((char*)&Ks[0][0] + (key+32)*256 + off) = lo.v;
    }
    {
      int d = tid & 127, kq = tid >> 7;           // 128 dims x 4 key-octets
      const float* vcs = Vc + (size_t)bbg*NBLK*DIM + d;
      union { ushort_t u[8]; uint4 v; } hi, lo;
#pragma unroll
      for (int kk = 0; kk < 8; ++kk){
        float f = vcs[(kq*8 + kk)*DIM];
        ushort_t hh = b16(f);
        hi.u[kk] = hh; lo.u[kk] = b16(f - fb(hh));
      }
      *(uint4*)&VcTh[d*VCS + kq*8] = hi.v;
      *(uint4*)&VcTl[d*VCS + kq*8] = lo.v;
    }
  }

  // ---- Q fragments (pre-scaled by SCALE*log2e) + gates -----------------
  const float* qrow0 = q + ((size_t)(bb*SEQ + qb*64 + qh2*32 + l15)*QH + g*NH + h)*DIM;
  const float* qrow1 = qrow0 + (size_t)16*QH*DIM;
  int gcol = 1 + role;
  bf16x8 qfrag0[4], qfrag1[4], qlo0[4], qlo1[4];
  float gp0 = 0.f, gp1 = 0.f, gc0 = 0.f, gc1 = 0.f;
#pragma unroll
  for (int kc = 0; kc < 4; ++kc){
    int d0 = kc*32 + quad*8;
    float4 a0 = *(const float4*)(qrow0 + d0);
    float4 a1 = *(const float4*)(qrow0 + d0 + 4);
    float4 b0 = *(const float4*)(qrow1 + d0);
    float4 b1 = *(const float4*)(qrow1 + d0 + 4);
    float qa[8] = {a0.x,a0.y,a0.z,a0.w,a1.x,a1.y,a1.z,a1.w};
    float qc[8] = {b0.x,b0.y,b0.z,b0.w,b1.x,b1.y,b1.z,b1.w};
#pragma unroll
    for (int jj = 0; jj < 8; ++jj){
      float wg = w_gate[(d0+jj)*3 + gcol];
      gp0 += qa[jj]*wg; gp1 += qc[jj]*wg;
    }
    if (role == 0){
#pragma unroll
      for (int jj = 0; jj < 8; ++jj){
        float w0 = w_gate[(d0+jj)*3];
        gc0 += qa[jj]*w0; gc1 += qc[jj]*w0;
      }
      union { ushort_t u[8]; bf16x8 v; } h0, l0, h1, l1;
#pragma unroll
      for (int e = 0; e < 8; ++e){
        float s0f = qa[e]*QSC; ushort_t hh0 = b16(s0f);
        h0.u[e] = hh0; l0.u[e] = b16(s0f - fb(hh0));
        float s1f = qc[e]*QSC; ushort_t hh1 = b16(s1f);
        h1.u[e] = hh1; l1.u[e] = b16(s1f - fb(hh1));
      }
      qfrag0[kc] = h0.v; qlo0[kc] = l0.v;
      qfrag1[kc] = h1.v; qlo1[kc] = l1.v;
    } else {
      union { unsigned uu[4]; bf16x8 v8; } t0, t1;
#pragma unroll
      for (int p2 = 0; p2 < 4; ++p2){
        t0.uu[p2] = pkbf(qa[2*p2]*QSC, qa[2*p2+1]*QSC);
        t1.uu[p2] = pkbf(qc[2*p2]*QSC, qc[2*p2+1]*QSC);
      }
      qfrag0[kc] = t0.v8; qfrag1[kc] = t1.v8;
    }
  }
  gp0 += __shfl_xor(gp0,16); gp0 += __shfl_xor(gp0,32);
  gp1 += __shfl_xor(gp1,16); gp1 += __shfl_xor(gp1,32);
  if (quad == 0){
    gbuf[w*32 + l15]      = 1.f/(1.f + __expf(-(gp0 + b_gate[gcol])));
    gbuf[w*32 + 16 + l15] = 1.f/(1.f + __expf(-(gp1 + b_gate[gcol])));
  }
  float g0c0 = 0.f, g0c1 = 0.f;
  if (role == 0){
    gc0 += __shfl_xor(gc0,16); gc0 += __shfl_xor(gc0,32);
    gc1 += __shfl_xor(gc1,16); gc1 += __shfl_xor(gc1,32);
    g0c0 = 1.f/(1.f + __expf(-(gc0 + b_gate[0])));
    g0c1 = 1.f/(1.f + __expf(-(gc1 + b_gate[0])));
  }
  __syncthreads();   // publishes gbuf + cmp tiles
  float gl0[4], gl1[4];
#pragma unroll
  for (int r = 0; r < 4; ++r){
    gl0[r] = gbuf[w*32 + quad*4 + r];
    gl1[r] = gbuf[w*32 + 16 + quad*4 + r];
  }

  const f32x4 zero4 = {0.f,0.f,0.f,0.f};
  f32x4 cp0[2], cp1[2];      // cmp g0*P_norm, kept across slc loop
  cp0[0] = zero4; cp0[1] = zero4; cp1[0] = zero4; cp1[1] = zero4;

  // ======== role0 cmp phase: hi/lo QK^T, softmax, pooled, top-k =============
  if (role == 0){
    f32x4 c0[2], c1[2];
    c0[0]=zero4; c0[1]=zero4; c1[0]=zero4; c1[1]=zero4;
#pragma unroll
    for (int kc = 0; kc < 4; ++kc){
#pragma unroll
      for (int nt = 0; nt < 2; ++nt){
        bf16x8 ah = *(bf16x8*)((char*)&Ks[0][0] + (nt*16 + l15)*256
                               + ((kc*64 + quad*16) ^ xr));
        bf16x8 al = *(bf16x8*)((char*)&Ks[0][0] + (nt*16 + l15 + 32)*256
                               + ((kc*64 + quad*16) ^ xr));
        c0[nt] = __builtin_amdgcn_mfma_f32_16x16x32_bf16(ah, qfrag0[kc], c0[nt], 0, 0, 0);
        c0[nt] = __builtin_amdgcn_mfma_f32_16x16x32_bf16(ah, qlo0[kc],   c0[nt], 0, 0, 0);
        c0[nt] = __builtin_amdgcn_mfma_f32_16x16x32_bf16(al, qfrag0[kc], c0[nt], 0, 0, 0);
        c1[nt] = __builtin_amdgcn_mfma_f32_16x16x32_bf16(ah, qfrag1[kc], c1[nt], 0, 0, 0);
        c1[nt] = __builtin_amdgcn_mfma_f32_16x16x32_bf16(ah, qlo1[kc],   c1[nt], 0, 0, 0);
        c1[nt] = __builtin_amdgcn_mfma_f32_16x16x32_bf16(al, qfrag1[kc], c1[nt], 0, 0, 0);
      }
    }
    // one-shot softmax over 32 keys (log2 domain)
    float mx0 = -INFINITY, mx1 = -INFINITY;
#pragma unroll
    for (int nt = 0; nt < 2; ++nt)
#pragma unroll
      for (int r = 0; r < 4; ++r){
        mx0 = fmaxf(mx0, c0[nt][r]); mx1 = fmaxf(mx1, c1[nt][r]);
      }
    mx0 = fmaxf(mx0, __shfl_xor(mx0,16)); mx0 = fmaxf(mx0, __shfl_xor(mx0,32));
    mx1 = fmaxf(mx1, __shfl_xor(mx1,16)); mx1 = fmaxf(mx1, __shfl_xor(mx1,32));
    float s0 = 0.f, s1 = 0.f;
#pragma unroll
    for (int nt = 0; nt < 2; ++nt)
#pragma unroll
      for (int r = 0; r < 4; ++r){
        float p0v = exp2f(c0[nt][r] - mx0); c0[nt][r] = p0v; s0 += p0v;
        float p1v = exp2f(c1[nt][r] - mx1); c1[nt][r] = p1v; s1 += p1v;
      }
    s0 += __shfl_xor(s0,16); s0 += __shfl_xor(s0,32);
    s1 += __shfl_xor(s1,16); s1 += __shfl_xor(s1,32);
    float ip0 = 1.f/s0, ip1 = 1.f/s1;
    float ig0 = g0c0*ip0, ig1 = g0c1*ip1;
#pragma unroll
    for (int nt = 0; nt < 2; ++nt)
#pragma unroll
      for (int r = 0; r < 4; ++r){
        cp0[nt][r] = c0[nt][r]*ig0;
        cp1[nt][r] = c1[nt][r]*ig1;
        float t = c0[nt][r]*ip0 + c1[nt][r]*ip1;     // ungated Pn sums
        t += __shfl_xor(t,1); t += __shfl_xor(t,2);
        t += __shfl_xor(t,4); t += __shfl_xor(t,8);
        if (l15 == 0) pw[w][nt*16 + quad*4 + r] = t;
      }
    __syncthreads();   // pw ready
    // top-k on wave 0 (lax.top_k tie rule)
    if (tid < 64){
      int n = lane;
      float val = -INFINITY;
      if (n < NBLK){
        float sm = 0.f;
#pragma unroll
        for (int w2 = 0; w2 < 8; ++w2) sm += pw[w2][n];
        val = sm;
      }
      for (int t = 0; t < NTOP; ++t){
        float bv = val; int bi = n;
        for (int mm = 1; mm < 32; mm <<= 1){
          float ov = __shfl_xor(bv, mm);
          int   oi = __shfl_xor(bi, mm);
          if (ov > bv || (ov == bv && oi < bi)){ bv = ov; bi = oi; }
        }
        if (lane == 0) idxs[t] = bi;
        if (n == bi) val = -INFINITY;
      }
    }
    __syncthreads();   // idxs ready; cmp reads of Ks[0] done -> restage ok
  }

  const ushort_t* kbase  = Kb + (size_t)bbg*SEQ*DIM;
  const ushort_t* vtbase = VT + (size_t)bbg*DIM*SEQ;

  int kb0 = (qb >= 8) ? (qb - 8) : 0;
  int nph = (role == 0) ? NTOP : (qb - kb0 + 1);
  int qi0 = qh2*32 + l15, qi1 = qi0 + 16;   // lane-local query indices

  float m10 = -INFINITY, l10 = 0.f, m11 = -INFINITY, l11 = 0.f;
  f32x4 oacc0[8], oacc1[8];
#pragma unroll
  for (int dt = 0; dt < 8; ++dt){ oacc0[dt] = zero4; oacc1[dt] = zero4; }

  // staging: 512 threads x 2 units x 16B per tile; LDS dest linear
  // (wave-uniform base), global src per-lane & pre-swizzled by prep_k.
  auto stage = [&](int bufi, int kb_){
    const ushort_t* ksrc = kbase + (size_t)kb_*64*DIM;
#pragma unroll
    for (int jj = 0; jj < 2; ++jj)          // K tile: 1024 16B units
      async16(&Ks[bufi][(jj*512 + w*64)*8], ksrc + (size_t)(tid + jj*512)*8);
    const ushort_t* vsrc = vtbase + kb_*64;
#pragma unroll
    for (int jj = 0; jj < 2; ++jj){         // VT tile: [d=128][64]
      int i = tid + jj*512;
      int d = i >> 3, sg = i & 7;
      async16(&VTs[bufi][(jj*512 + w*64)*8], vsrc + (size_t)d*SEQ + sg*8);
    }
  };

  stage(0, (role == 0) ? idxs[0] : kb0);

  for (int t = 0; t < nph; ++t){
    int cur = t & 1;
    int kb = (role == 0) ? idxs[t] : (kb0 + t);
    // vmcnt(0)+lgkmcnt(0) drain + barrier: buf[cur] resident; buf[cur^1] free.
    __syncthreads();
    if (t+1 < nph){
      int kbn = (role == 0) ? idxs[t+1] : (kb0 + t + 1);
      stage(cur ^ 1, kbn);                  // flies under this phase
    }
    __builtin_amdgcn_sched_barrier(0);      // pin prefetch issue early

    // ---- QK^T swapped: mfma(K, Q); K A-frags shared across both q-tiles ----
    f32x4 sacc0[4], sacc1[4];
#pragma unroll
    for (int nt = 0; nt < 4; ++nt){ sacc0[nt] = zero4; sacc1[nt] = zero4; }
    __builtin_amdgcn_s_setprio(1);
#pragma unroll
    for (int kc = 0; kc < 4; ++kc){
#pragma unroll
      for (int nt = 0; nt < 4; ++nt){
        bf16x8 a = *(bf16x8*)((char*)&Ks[cur][0] + (nt*16 + l15)*256
                              + ((kc*64 + quad*16) ^ xr));
        sacc0[nt] = __builtin_amdgcn_mfma_f32_16x16x32_bf16(a, qfrag0[kc], sacc0[nt], 0, 0, 0);
        sacc1[nt] = __builtin_amdgcn_mfma_f32_16x16x32_bf16(a, qfrag1[kc], sacc1[nt], 0, 0, 0);
      }
    }
    __builtin_amdgcn_s_setprio(0);

    bool mlow  = (role == 1) && (kb == qb - 8);   // valid: key >= qi
    bool mhigh = (role == 1) && (kb == qb);       // valid: key <= qi
    bool domask = mlow | mhigh;

    // ---- lane-local softmax per q-tile (scores already in log2 domain) ----
    auto softmax_qt = [&](f32x4* sc2, float& m1r, float& l1r, int qi_l,
                          bool& skipped) -> float {
      float mx = -INFINITY;
      if (domask){
#pragma unroll
        for (int nt = 0; nt < 4; ++nt)
#pragma unroll
          for (int r = 0; r < 4; ++r){
            int key = nt*16 + quad*4 + r;
            float sv = sc2[nt][r];
            bool valid = (!mlow || key >= qi_l) && (!mhigh || key <= qi_l);
            sv = valid ? sv : -INFINITY;
            sc2[nt][r] = sv;
            mx = fmaxf(mx, sv);
          }
      } else {
#pragma unroll
        for (int nt = 0; nt < 4; ++nt)
#pragma unroll
          for (int r = 0; r < 4; ++r) mx = fmaxf(mx, sc2[nt][r]);
      }
      mx = fmaxf(mx, __shfl_xor(mx, 16));
      mx = fmaxf(mx, __shfl_xor(mx, 32));
      float al = 1.f;
      skipped = __all(mx <= m1r + 8.f);     // defer-max: P bounded by 2^8
      if (!skipped){
        float mn = fmaxf(m1r, mx);
        al = exp2f(m1r - mn);
        m1r = mn;
      }
      float s0 = 0.f;
#pragma unroll
      for (int nt = 0; nt < 4; ++nt)
#pragma unroll
        for (int r = 0; r < 4; ++r){
          float pe = exp2f(sc2[nt][r] - m1r);   // masked -> 0
          sc2[nt][r] = pe;
          s0 += pe;
        }
      s0 += __shfl_xor(s0, 16);
      s0 += __shfl_xor(s0, 32);
      l1r = l1r*al + s0;
      return al;
    };
    bool sk0, sk1;
    float al0 = softmax_qt(sacc0, m10, l10, qi0, sk0);
    float al1 = softmax_qt(sacc1, m11, l11, qi1, sk1);

    // ---- P -> LDS bf16, packed b64 (row = query; wave-private slab) ----
#pragma unroll
    for (int nt = 0; nt < 4; ++nt){
      uint2 p0, p1;
      p0.x = pkbf(sacc0[nt][0], sacc0[nt][1]);
      p0.y = pkbf(sacc0[nt][2], sacc0[nt][3]);
      p1.x = pkbf(sacc1[nt][0], sacc1[nt][1]);
      p1.y = pkbf(sacc1[nt][2], sacc1[nt][3]);
      *(uint2*)&Ps[(w*32 + l15)*VP + nt*16 + quad*4] = p0;
      *(uint2*)&Ps[(w*32 + 16 + l15)*VP + nt*16 + quad*4] = p1;
    }

    // ---- O rescale (skipped when defer-max held) ----
    if (!sk0){
      float ar[4];
#pragma unroll
      for (int r = 0; r < 4; ++r) ar[r] = __shfl(al0, quad*4 + r);
#pragma unroll
      for (int dt = 0; dt < 8; ++dt)
#pragma unroll
        for (int r = 0; r < 4; ++r) oacc0[dt][r] *= ar[r];
    }
    if (!sk1){
      float ar[4];
#pragma unroll
      for (int r = 0; r < 4; ++r) ar[r] = __shfl(al1, quad*4 + r);
#pragma unroll
      for (int dt = 0; dt < 8; ++dt)
#pragma unroll
        for (int r = 0; r < 4; ++r) oacc1[dt][r] *= ar[r];
    }

    // ---- PV: V B-frags shared across both q-tiles ----
#pragma unroll
    for (int kc2 = 0; kc2 < 2; ++kc2){
      bf16x8 pa0 = *(bf16x8*)&Ps[(w*32 + l15)*VP + kc2*32 + quad*8];
      bf16x8 pa1 = *(bf16x8*)&Ps[(w*32 + 16 + l15)*VP + kc2*32 + quad*8];
      __builtin_amdgcn_s_setprio(1);
#pragma unroll
      for (int dt = 0; dt < 8; ++dt){
        bf16x8 vb8 = *(bf16x8*)((char*)&VTs[cur][0] + (dt*16 + l15)*128
                                + ((kc2*64 + quad*16) ^ xr));
        oacc0[dt] = __builtin_amdgcn_mfma_f32_16x16x32_bf16(pa0, vb8, oacc0[dt], 0, 0, 0);
        oacc1[dt] = __builtin_amdgcn_mfma_f32_16x16x32_bf16(pa1, vb8, oacc1[dt], 0, 0, 0);
      }
      __builtin_amdgcn_s_setprio(0);
    }
  }

  // ---- epilogue ----
  float lr0[4], lr1[4];
#pragma unroll
  for (int r = 0; r < 4; ++r){
    lr0[r] = __shfl(l10, quad*4 + r);
    lr1[r] = __shfl(l11, quad*4 + r);
  }
  if (role == 0){
    // fold slc gate + norm into oacc, then add cmp branch via hi/lo PV
    float a0[4], a1[4];
#pragma unroll
    for (int r = 0; r < 4; ++r){ a0[r] = gl0[r]/lr0[r]; a1[r] = gl1[r]/lr1[r]; }
#pragma unroll
    for (int dt = 0; dt < 8; ++dt)
#pragma unroll
      for (int r = 0; r < 4; ++r){ oacc0[dt][r] *= a0[r]; oacc1[dt][r] *= a1[r]; }
    // write cmp P (g0-scaled, hi/lo) into own wave slab; same-wave RAW only
#pragma unroll
    for (int nt = 0; nt < 2; ++nt){
      union { ushort_t u[4]; uint2 v; } h0, l0, h1, l1;
#pragma unroll
      for (int r = 0; r < 4; ++r){
        ushort_t hh0 = b16(cp0[nt][r]);
        h0.u[r] = hh0; l0.u[r] = b16(cp0[nt][r] - fb(hh0));
        ushort_t hh1 = b16(cp1[nt][r]);
        h1.u[r] = hh1; l1.u[r] = b16(cp1[nt][r] - fb(hh1));
      }
      *(uint2*)&Ps[(w*32 + l15)*VP + nt*16 + quad*4]      = h0.v;
      *(uint2*)&Ps[(w*32 + l15)*VP + 32 + nt*16 + quad*4] = l0.v;
      *(uint2*)&Ps[(w*32 + 16 + l15)*VP + nt*16 + quad*4]      = h1.v;
      *(uint2*)&Ps[(w*32 + 16 + l15)*VP + 32 + nt*16 + quad*4] = l1.v;
    }
    bf16x8 pah0 = *(bf16x8*)&Ps[(w*32 + l15)*VP + quad*8];
    bf16x8 pal0 = *(bf16x8*)&Ps[(w*32 + l15)*VP + 32 + quad*8];
    bf16x8 pah1 = *(bf16x8*)&Ps[(w*32 + 16 + l15)*VP + quad*8];
    bf16x8 pal1 = *(bf16x8*)&Ps[(w*32 + 16 + l15)*VP + 32 + quad*8];
#pragma unroll
    for (int dt = 0; dt < 8; ++dt){
      bf16x8 vbh = *(bf16x8*)&VcTh[(dt*16 + l15)*VCS + quad*8];
      bf16x8 vbl = *(bf16x8*)&VcTl[(dt*16 + l15)*VCS + quad*8];
      oacc0[dt] = __builtin_amdgcn_mfma_f32_16x16x32_bf16(pah0, vbh, oacc0[dt], 0, 0, 0);
      oacc0[dt] = __builtin_amdgcn_mfma_f32_16x16x32_bf16(pah0, vbl, oacc0[dt], 0, 0, 0);
      oacc0[dt] = __builtin_amdgcn_mfma_f32_16x16x32_bf16(pal0, vbh, oacc0[dt], 0, 0, 0);
      oacc1[dt] = __builtin_amdgcn_mfma_f32_16x16x32_bf16(pah1, vbh, oacc1[dt], 0, 0, 0);
      oacc1[dt] = __builtin_amdgcn_mfma_f32_16x16x32_bf16(pah1, vbl, oacc1[dt], 0, 0, 0);
      oacc1[dt] = __builtin_amdgcn_mfma_f32_16x16x32_bf16(pal1, vbh, oacc1[dt], 0, 0, 0);
    }
#pragma unroll
    for (int r = 0; r < 4; ++r){
      size_t ob0 = ((size_t)(bb*SEQ + qb*64 + qh2*32 + quad*4 + r)*QH + g*NH + h)*DIM + l15;
      size_t ob1 = ob0 + (size_t)16*QH*DIM;
      float* op0 = slcbuf + ob0;            // unique writer; full coverage
      float* op1 = slcbuf + ob1;
#pragma unroll
      for (int dt = 0; dt < 8; ++dt){
        op0[dt*16] = oacc0[dt][r];
        op1[dt*16] = oacc1[dt][r];
      }
    }
  } else {
#pragma unroll
    for (int r = 0; r < 4; ++r){
      float s20 = gl0[r] / lr0[r];
      float s21 = gl1[r] / lr1[r];
      size_t ob0 = ((size_t)(bb*SEQ + qb*64 + qh2*32 + quad*4 + r)*QH + g*NH + h)*DIM + l15;
      size_t ob1 = ob0 + (size_t)16*QH*DIM;
      float* op0 = out + ob0;               // unique writer; OVERWRITE
      float* op1 = out + ob1;
#pragma unroll
      for (int dt = 0; dt < 8; ++dt){
        op0[dt*16] = s20 * oacc0[dt][r];
        op1[dt*16] = s21 * oacc1[dt][r];
      }
    }
  }
}

// ---------------- kernel 2: merge (out += slcbuf) ---------------------------
__global__ __launch_bounds__(256) void merge_k(const float* __restrict__ slcbuf,
                                               float* __restrict__ out){
  int i = blockIdx.x * 256 + threadIdx.x;   // over 4096*8*128/4 float4s
  float4 a = ((const float4*)slcbuf)[i];
  float4 b = ((float4*)out)[i];
  b.x += a.x; b.y += a.y; b.z += a.z; b.w += a.w;
  ((float4*)out)[i] = b;
}

extern "C" void kernel_launch(void* const* d_in, const int* in_sizes, int n_in,
                              void* d_out, int out_size, void* d_ws, size_t ws_size,
                              hipStream_t stream) {
  const float* q      = (const float*)d_in[0];
  const float* k      = (const float*)d_in[1];
  const float* v      = (const float*)d_in[2];
  const float* w_k    = (const float*)d_in[3];
  const float* b_k    = (const float*)d_in[4];
  const float* w_v    = (const float*)d_in[5];
  const float* b_v    = (const float*)d_in[6];
  const float* w_gate = (const float*)d_in[7];
  const float* b_gate = (const float*)d_in[8];
  float* out = (float*)d_out;

  float* ws     = (float*)d_ws;
  float* Kc     = ws;                        // 16384 f32
  float* Vc     = ws + 16384;                // 16384 f32
  float* slcbuf = ws + 49152;                // 4.19M f32 (16.8 MB)
  ushort_t* Kb  = (ushort_t*)(ws + 4243456); // 4*2048*128 bf16 (2 MB)
  ushort_t* VT  = Kb + 1048576;              // 4*128*2048 bf16 (2 MB)

  prep_k <<<256, 256, 0, stream>>>(k, v, w_k, b_k, w_v, b_v, Kb, VT, Kc, Vc);
  attn_k <<<256, 512, 0, stream>>>(q, Kb, VT, Kc, Vc, w_gate, b_gate, slcbuf, out);
  merge_k<<<4096, 256, 0, stream>>>(slcbuf, out);
}

// Round 6
// 161.933 us; speedup vs baseline: 1.9717x; 1.0272x over previous
//
#include <hip/hip_runtime.h>
#include <hip/hip_bf16.h>

// NSA forward, MI355X round 16. All inputs fp32, output fp32.
// r15 + attn_k software pipeline: PV deferred one phase (QK_t || PV_{t-1}
// overlap: MFMA pipe fed while softmax_t's VALU chain runs), V triple-ring,
// single P slab (in-order DS per wave), final-PV drain after loop; bitonic
// top-16 (15 stages vs 80 serial shuffles); tree max/sum in softmax.
// 3 kernels: prep (bf16 swizzle + compression), attn (cmp+slc | win), merge.
// Shapes: S=4096, seqlen=2048, qh=8, kvh=2, dim=128, blk=64, TOPK=16,
// window=(512,0).

#define SEQ   2048
#define NB    2
#define KV    2
#define NH    4
#define QH    8
#define DIM   128
#define NBLK  32
#define NQB   32
#define NTOP  16
#define SCALE 0.08838834764831845f   // 128^-0.5
#define QSC   0.12751831795244785f   // SCALE * log2(e)
#define VP    72                     // P/prep-T LDS row stride (bf16): pad 8
#define VCS   40                     // VcT LDS row stride (bf16): 32 + pad 8

typedef unsigned short ushort_t;
using bf16x8 = __attribute__((ext_vector_type(8))) short;
using f32x4  = __attribute__((ext_vector_type(4))) float;

__device__ __forceinline__ unsigned pkbf(float a, float b){
  union { __hip_bfloat162 h; unsigned u; } cv;
  cv.h = __float22bfloat162_rn(make_float2(a, b));
  return cv.u;
}
__device__ __forceinline__ ushort_t b16(float f){
  union { float f; unsigned i; } x; x.f = f;
  unsigned r = x.i + 0x7fffu + ((x.i >> 16) & 1u);   // RNE
  return (ushort_t)(r >> 16);
}
__device__ __forceinline__ float fb(ushort_t h){
  union { unsigned i; float f; } x; x.i = ((unsigned)h) << 16;
  return x.f;
}

// async 16B direct-to-LDS copy (per-lane global src, wave-uniform LDS base)
__device__ __forceinline__ void async16(ushort_t* l, const ushort_t* g){
  __builtin_amdgcn_global_load_lds(
      (const __attribute__((address_space(1))) unsigned int*)(size_t)g,
      (__attribute__((address_space(3))) unsigned int*)(size_t)l,
      16, 0, 0);
}

// -------- kernel 0: K/V bf16 preprocessing + block compression (fused) ------
// Kb row-major [bbg][row][128] bf16, each 256B row stored XOR-swizzled:
// byte ^= (row&7)<<4.  VT transposed [bbg][d][SEQ] bf16; within each 128B
// (64-seq) tile: byte ^= (d&7)<<4.  Also computes Kc/Vc (w_k/w_v-weighted
// row sums per 64-block) from the same float4 loads.
__global__ __launch_bounds__(256) void prep_k(
    const float* __restrict__ k, const float* __restrict__ v,
    const float* __restrict__ w_k, const float* __restrict__ b_k,
    const float* __restrict__ w_v, const float* __restrict__ b_v,
    ushort_t* __restrict__ Kb, ushort_t* __restrict__ VT,
    float* __restrict__ Kc, float* __restrict__ Vc)
{
  int blk = blockIdx.x;
  int db = blk & 1, rb = (blk >> 1) & 31, bbg = blk >> 6;
  int bb = bbg >> 1, g = bbg & 1;
  int tid = threadIdx.x;
  __shared__ ushort_t T[64*VP];    // [d 0..63][key 0..63], pad 8
  __shared__ float wks[64], wvs[64];
  __shared__ float accK[16][64], accV[16][64];

  if (tid < 64){ wks[tid] = w_k[tid]; wvs[tid] = w_v[tid]; }
  __syncthreads();

  float4 sk = {0,0,0,0}, sv = {0,0,0,0};
  for (int jj = 0; jj < 4; ++jj){
    int i = tid + jj*256;                 // 1024 float4 units (64 rows x 16)
    int r = i >> 4, ds = i & 15;
    size_t src = ((size_t)(bb*SEQ + rb*64 + r)*KV + g)*DIM + db*64 + ds*4;
    float4 kx = *(const float4*)(k + src);
    float4 vx = *(const float4*)(v + src);
    uint2 kk; kk.x = pkbf(kx.x,kx.y); kk.y = pkbf(kx.z,kx.w);
    size_t rowb = ((size_t)bbg*SEQ + rb*64 + r)*DIM*2;        // row base bytes
    int swz = (db*128 + ds*8) ^ ((r & 7) << 4);               // within-row
    *(uint2*)((char*)Kb + rowb + swz) = kk;
    unsigned v01 = pkbf(vx.x,vx.y), v23 = pkbf(vx.z,vx.w);
    T[(ds*4+0)*VP + r] = (ushort_t)(v01 & 0xffffu);
    T[(ds*4+1)*VP + r] = (ushort_t)(v01 >> 16);
    T[(ds*4+2)*VP + r] = (ushort_t)(v23 & 0xffffu);
    T[(ds*4+3)*VP + r] = (ushort_t)(v23 >> 16);
    float a = wks[r], b = wvs[r];
    sk.x += a*kx.x; sk.y += a*kx.y; sk.z += a*kx.z; sk.w += a*kx.w;
    sv.x += b*vx.x; sv.y += b*vx.y; sv.z += b*vx.z; sv.w += b*vx.w;
  }
  *(float4*)&accK[tid>>4][(tid&15)*4] = sk;
  *(float4*)&accV[tid>>4][(tid&15)*4] = sv;
  __syncthreads();

  for (int jj = 0; jj < 4; ++jj){
    int i = tid + jj*256;                 // 1024 8B units (64 d x 16)
    int d = i >> 4, seg = i & 15;
    uint2 u = *(uint2*)&T[d*VP + seg*4];
    size_t rowb = ((size_t)bbg*DIM + db*64 + d)*SEQ*2;        // d-row bytes
    int swz = (seg*8) ^ ((d & 7) << 4);                       // within 128B tile
    *(uint2*)((char*)VT + rowb + rb*128 + swz) = u;
  }

  size_t obase = ((size_t)(bbg*NBLK + rb))*DIM + db*64;
  if (tid < 64){
    float s = 0.f;
#pragma unroll
    for (int i = 0; i < 16; ++i) s += accK[i][tid];
    Kc[obase + tid] = s + b_k[0];
  } else if (tid < 128){
    int d = tid - 64;
    float s = 0.f;
#pragma unroll
    for (int i = 0; i < 16; ++i) s += accV[i][d];
    Vc[obase + d] = s + b_v[0];
  }
}

// ---- kernel 1: role-split (cmp+topk+slc) | win attention (MFMA) ------------
// grid 256, 512 threads. block = (bbg, qb, role); wave w: head w&3, qhalf w>>2.
// Swapped QK^T: C[col=l15=query][row=quad*4+r=key] -> lane-local softmax.
// Pipeline: phase t = { stage t+1 | QK_t | rescale+PV_{t-1} | softmax_t }.
// V triple-ring (stage t+1 while PV reads t-1); K double-buffer; single
// P slab per wave (DS in-order per wave: PV reads precede softmax writes).
// Layouts (m89/m91/m120): A[m=lane&15][k=quad*8+j], B[k=quad*8+j][n=lane&15],
// C[col=lane&15,row=quad*4+r]
__global__ __launch_bounds__(512, 2) void attn_k(
    const float* __restrict__ q, const ushort_t* __restrict__ Kb,
    const ushort_t* __restrict__ VT,
    const float* __restrict__ Kc, const float* __restrict__ Vc,
    const float* __restrict__ w_gate, const float* __restrict__ b_gate,
    float* __restrict__ slcbuf, float* __restrict__ out)
{
  int idx = blockIdx.x;             // 256 blocks
  int x = idx & 7, low = idx & 1, u = idx >> 3;
  int bbg = x >> 1;                 // (bb,g): same-bbg blocks share XCD pair
  int j = u*2 + low;                // 0..63
  int role = j >> 5;                // 0 = cmp+slc, 1 = win
  int qb = j & 31;
  int bb = bbg >> 1, g = bbg & 1;

  int tid = threadIdx.x;
  int lane = tid & 63, w = tid >> 6;        // wave 0..7
  int quad = lane >> 4, l15 = lane & 15;
  int h = w & 3, qh2 = w >> 2;              // head, query half
  int xr = (l15 & 7) << 4;                  // read-side XOR (matches prep_k)

  __shared__ ushort_t Ks[2][64*128];    // 32 KB K double buffer
  __shared__ ushort_t VTs[3][128*64];   // 48 KB V triple ring
  __shared__ ushort_t Ps[256*VP];       // 36 KB (per-wave 32-row slabs)
  __shared__ ushort_t VcTh[128*VCS];    // 10 KB cmp V^T hi
  __shared__ ushort_t VcTl[128*VCS];    // 10 KB cmp V^T lo
  __shared__ float pw[8][NBLK];         //  1 KB pooled partials per wave
  __shared__ float gbuf[256];
  __shared__ int   idxs[NTOP];

  // ---- role0: stage cmp tiles (Kc hi/lo -> Ks[0] rows 0-31/32-63; Vc -> VcT)
  if (role == 0){
    {
      int key = tid >> 4, dq = tid & 15;          // 32 keys x 16 dim-octets
      const float* kcs = Kc + ((size_t)bbg*NBLK + key)*DIM + dq*8;
      float4 f0 = *(const float4*)kcs, f1 = *(const float4*)(kcs + 4);
      float fe[8] = {f0.x,f0.y,f0.z,f0.w,f1.x,f1.y,f1.z,f1.w};
      union { ushort_t u[8]; uint4 v; } hi, lo;
#pragma unroll
      for (int e = 0; e < 8; ++e){
        ushort_t hh = b16(fe[e]);
        hi.u[e] = hh; lo.u[e] = b16(fe[e] - fb(hh));
      }
      int off = (dq*16) ^ ((key & 7) << 4);
      *(uint4*)((char*)&Ks[0][0] + key*256 + off) = hi.v;
      *(uint4*)((char*)&Ks[0][0] + (key+32)*256 + off) = lo.v;
    }
    {
      int d = tid & 127, kq = tid >> 7;           // 128 dims x 4 key-octets
      const float* vcs = Vc + (size_t)bbg*NBLK*DIM + d;
      union { ushort_t u[8]; uint4 v; } hi, lo;
#pragma unroll
      for (int kk = 0; kk < 8; ++kk){
        float f = vcs[(kq*8 + kk)*DIM];
        ushort_t hh = b16(f);
        hi.u[kk] = hh; lo.u[kk] = b16(f - fb(hh));
      }
      *(uint4*)&VcTh[d*VCS + kq*8] = hi.v;
      *(uint4*)&VcTl[d*VCS + kq*8] = lo.v;
    }
  }

  // ---- Q fragments (pre-scaled by SCALE*log2e) + gates -----------------
  const float* qrow0 = q + ((size_t)(bb*SEQ + qb*64 + qh2*32 + l15)*QH + g*NH + h)*DIM;
  const float* qrow1 = qrow0 + (size_t)16*QH*DIM;
  int gcol = 1 + role;
  bf16x8 qfrag0[4], qfrag1[4], qlo0[4], qlo1[4];
  float gp0 = 0.f, gp1 = 0.f, gc0 = 0.f, gc1 = 0.f;
#pragma unroll
  for (int kc = 0; kc < 4; ++kc){
    int d0 = kc*32 + quad*8;
    float4 a0 = *(const float4*)(qrow0 + d0);
    float4 a1 = *(const float4*)(qrow0 + d0 + 4);
    float4 b0 = *(const float4*)(qrow1 + d0);
    float4 b1 = *(const float4*)(qrow1 + d0 + 4);
    float qa[8] = {a0.x,a0.y,a0.z,a0.w,a1.x,a1.y,a1.z,a1.w};
    float qc[8] = {b0.x,b0.y,b0.z,b0.w,b1.x,b1.y,b1.z,b1.w};
#pragma unroll
    for (int jj = 0; jj < 8; ++jj){
      float wg = w_gate[(d0+jj)*3 + gcol];
      gp0 += qa[jj]*wg; gp1 += qc[jj]*wg;
    }
    if (role == 0){
#pragma unroll
      for (int jj = 0; jj < 8; ++jj){
        float w0 = w_gate[(d0+jj)*3];
        gc0 += qa[jj]*w0; gc1 += qc[jj]*w0;
      }
      union { ushort_t u[8]; bf16x8 v; } h0, l0, h1, l1;
#pragma unroll
      for (int e = 0; e < 8; ++e){
        float s0f = qa[e]*QSC; ushort_t hh0 = b16(s0f);
        h0.u[e] = hh0; l0.u[e] = b16(s0f - fb(hh0));
        float s1f = qc[e]*QSC; ushort_t hh1 = b16(s1f);
        h1.u[e] = hh1; l1.u[e] = b16(s1f - fb(hh1));
      }
      qfrag0[kc] = h0.v; qlo0[kc] = l0.v;
      qfrag1[kc] = h1.v; qlo1[kc] = l1.v;
    } else {
      union { unsigned uu[4]; bf16x8 v8; } t0, t1;
#pragma unroll
      for (int p2 = 0; p2 < 4; ++p2){
        t0.uu[p2] = pkbf(qa[2*p2]*QSC, qa[2*p2+1]*QSC);
        t1.uu[p2] = pkbf(qc[2*p2]*QSC, qc[2*p2+1]*QSC);
      }
      qfrag0[kc] = t0.v8; qfrag1[kc] = t1.v8;
    }
  }
  gp0 += __shfl_xor(gp0,16); gp0 += __shfl_xor(gp0,32);
  gp1 += __shfl_xor(gp1,16); gp1 += __shfl_xor(gp1,32);
  if (quad == 0){
    gbuf[w*32 + l15]      = 1.f/(1.f + __expf(-(gp0 + b_gate[gcol])));
    gbuf[w*32 + 16 + l15] = 1.f/(1.f + __expf(-(gp1 + b_gate[gcol])));
  }
  float g0c0 = 0.f, g0c1 = 0.f;
  if (role == 0){
    gc0 += __shfl_xor(gc0,16); gc0 += __shfl_xor(gc0,32);
    gc1 += __shfl_xor(gc1,16); gc1 += __shfl_xor(gc1,32);
    g0c0 = 1.f/(1.f + __expf(-(gc0 + b_gate[0])));
    g0c1 = 1.f/(1.f + __expf(-(gc1 + b_gate[0])));
  }
  __syncthreads();   // publishes gbuf + cmp tiles
  float gl0[4], gl1[4];
#pragma unroll
  for (int r = 0; r < 4; ++r){
    gl0[r] = gbuf[w*32 + quad*4 + r];
    gl1[r] = gbuf[w*32 + 16 + quad*4 + r];
  }

  const f32x4 zero4 = {0.f,0.f,0.f,0.f};
  f32x4 cp0[2], cp1[2];      // cmp g0*P_norm, kept across slc loop
  cp0[0] = zero4; cp0[1] = zero4; cp1[0] = zero4; cp1[1] = zero4;

  // ======== role0 cmp phase: hi/lo QK^T, softmax, pooled, top-k =============
  if (role == 0){
    f32x4 c0[2], c1[2];
    c0[0]=zero4; c0[1]=zero4; c1[0]=zero4; c1[1]=zero4;
#pragma unroll
    for (int kc = 0; kc < 4; ++kc){
#pragma unroll
      for (int nt = 0; nt < 2; ++nt){
        bf16x8 ah = *(bf16x8*)((char*)&Ks[0][0] + (nt*16 + l15)*256
                               + ((kc*64 + quad*16) ^ xr));
        bf16x8 al = *(bf16x8*)((char*)&Ks[0][0] + (nt*16 + l15 + 32)*256
                               + ((kc*64 + quad*16) ^ xr));
        c0[nt] = __builtin_amdgcn_mfma_f32_16x16x32_bf16(ah, qfrag0[kc], c0[nt], 0, 0, 0);
        c0[nt] = __builtin_amdgcn_mfma_f32_16x16x32_bf16(ah, qlo0[kc],   c0[nt], 0, 0, 0);
        c0[nt] = __builtin_amdgcn_mfma_f32_16x16x32_bf16(al, qfrag0[kc], c0[nt], 0, 0, 0);
        c1[nt] = __builtin_amdgcn_mfma_f32_16x16x32_bf16(ah, qfrag1[kc], c1[nt], 0, 0, 0);
        c1[nt] = __builtin_amdgcn_mfma_f32_16x16x32_bf16(ah, qlo1[kc],   c1[nt], 0, 0, 0);
        c1[nt] = __builtin_amdgcn_mfma_f32_16x16x32_bf16(al, qfrag1[kc], c1[nt], 0, 0, 0);
      }
    }
    // one-shot softmax over 32 keys (log2 domain)
    float mx0 = -INFINITY, mx1 = -INFINITY;
#pragma unroll
    for (int nt = 0; nt < 2; ++nt)
#pragma unroll
      for (int r = 0; r < 4; ++r){
        mx0 = fmaxf(mx0, c0[nt][r]); mx1 = fmaxf(mx1, c1[nt][r]);
      }
    mx0 = fmaxf(mx0, __shfl_xor(mx0,16)); mx0 = fmaxf(mx0, __shfl_xor(mx0,32));
    mx1 = fmaxf(mx1, __shfl_xor(mx1,16)); mx1 = fmaxf(mx1, __shfl_xor(mx1,32));
    float s0 = 0.f, s1 = 0.f;
#pragma unroll
    for (int nt = 0; nt < 2; ++nt)
#pragma unroll
      for (int r = 0; r < 4; ++r){
        float p0v = exp2f(c0[nt][r] - mx0); c0[nt][r] = p0v; s0 += p0v;
        float p1v = exp2f(c1[nt][r] - mx1); c1[nt][r] = p1v; s1 += p1v;
      }
    s0 += __shfl_xor(s0,16); s0 += __shfl_xor(s0,32);
    s1 += __shfl_xor(s1,16); s1 += __shfl_xor(s1,32);
    float ip0 = 1.f/s0, ip1 = 1.f/s1;
    float ig0 = g0c0*ip0, ig1 = g0c1*ip1;
#pragma unroll
    for (int nt = 0; nt < 2; ++nt)
#pragma unroll
      for (int r = 0; r < 4; ++r){
        cp0[nt][r] = c0[nt][r]*ig0;
        cp1[nt][r] = c1[nt][r]*ig1;
        float t = c0[nt][r]*ip0 + c1[nt][r]*ip1;     // ungated Pn sums
        t += __shfl_xor(t,1); t += __shfl_xor(t,2);
        t += __shfl_xor(t,4); t += __shfl_xor(t,8);
        if (l15 == 0) pw[w][nt*16 + quad*4 + r] = t;
      }
    __syncthreads();   // pw ready
    // top-16 on wave 0: bitonic sort of 32 (desc, tie: lower idx), 15 stages
    if (tid < 64){
      int n = lane;
      float val = -INFINITY;
      if (n < NBLK){
        float sm = 0.f;
#pragma unroll
        for (int w2 = 0; w2 < 8; ++w2) sm += pw[w2][n];
        val = sm;
      }
      int idxv = n;
      for (int kk = 2; kk <= 32; kk <<= 1){
        for (int jj2 = kk >> 1; jj2 > 0; jj2 >>= 1){
          float pv = __shfl_xor(val, jj2);
          int   pi = __shfl_xor(idxv, jj2);
          bool lower = (lane & jj2) == 0;
          bool desc  = (lane & kk) == 0;
          bool iwin  = (val > pv) || (val == pv && idxv < pi);
          bool keep  = (lower == desc) ? iwin : !iwin;
          if (!keep){ val = pv; idxv = pi; }
        }
      }
      if (lane < NTOP) idxs[lane] = idxv;
    }
    __syncthreads();   // idxs ready; cmp reads of Ks[0] done -> restage ok
  }

  const ushort_t* kbase  = Kb + (size_t)bbg*SEQ*DIM;
  const ushort_t* vtbase = VT + (size_t)bbg*DIM*SEQ;

  int kb0 = (qb >= 8) ? (qb - 8) : 0;
  int nph = (role == 0) ? NTOP : (qb - kb0 + 1);
  int qi0 = qh2*32 + l15, qi1 = qi0 + 16;   // lane-local query indices

  float m10 = -INFINITY, l10 = 0.f, m11 = -INFINITY, l11 = 0.f;
  f32x4 oacc0[8], oacc1[8];
#pragma unroll
  for (int dt = 0; dt < 8; ++dt){ oacc0[dt] = zero4; oacc1[dt] = zero4; }

  // staging: 512 threads x 2 units x 16B per tile; LDS dest linear
  // (wave-uniform base), global src per-lane & pre-swizzled by prep_k.
  auto stage = [&](int kbuf, int vbuf, int kb_){
    const ushort_t* ksrc = kbase + (size_t)kb_*64*DIM;
#pragma unroll
    for (int jj = 0; jj < 2; ++jj)          // K tile: 1024 16B units
      async16(&Ks[kbuf][(jj*512 + w*64)*8], ksrc + (size_t)(tid + jj*512)*8);
    const ushort_t* vsrc = vtbase + kb_*64;
#pragma unroll
    for (int jj = 0; jj < 2; ++jj){         // VT tile: [d=128][64]
      int i = tid + jj*512;
      int d = i >> 3, sg = i & 7;
      async16(&VTs[vbuf][(jj*512 + w*64)*8], vsrc + (size_t)d*SEQ + sg*8);
    }
  };

  stage(0, 0, (role == 0) ? idxs[0] : kb0);

  float alp0 = 1.f, alp1 = 1.f;
  bool  skp0 = true,  skp1 = true;
  int vprev = 2, vcur = 0, vnext = 1;       // V ring indices

  for (int t = 0; t < nph; ++t){
    int kb = (role == 0) ? idxs[t] : (kb0 + t);
    // vmcnt(0)+lgkmcnt(0) drain + barrier: tile t resident; old bufs free.
    __syncthreads();
    if (t+1 < nph){
      int kbn = (role == 0) ? idxs[t+1] : (kb0 + t + 1);
      stage((t+1) & 1, vnext, kbn);         // flies under this phase
    }
    __builtin_amdgcn_sched_barrier(0);      // pin prefetch issue early

    // ---- QK_t swapped: mfma(K, Q); K A-frags shared across both q-tiles ----
    f32x4 sacc0[4], sacc1[4];
#pragma unroll
    for (int nt = 0; nt < 4; ++nt){ sacc0[nt] = zero4; sacc1[nt] = zero4; }
    __builtin_amdgcn_s_setprio(1);
#pragma unroll
    for (int kc = 0; kc < 4; ++kc){
#pragma unroll
      for (int nt = 0; nt < 4; ++nt){
        bf16x8 a = *(bf16x8*)((char*)&Ks[t & 1][0] + (nt*16 + l15)*256
                              + ((kc*64 + quad*16) ^ xr));
        sacc0[nt] = __builtin_amdgcn_mfma_f32_16x16x32_bf16(a, qfrag0[kc], sacc0[nt], 0, 0, 0);
        sacc1[nt] = __builtin_amdgcn_mfma_f32_16x16x32_bf16(a, qfrag1[kc], sacc1[nt], 0, 0, 0);
      }
    }
    __builtin_amdgcn_s_setprio(0);

    // ---- deferred: rescale O by alpha_{t-1}, then PV_{t-1} ----
    // (independent of QK_t/softmax_t -> overlaps softmax's VALU chain;
    //  slab reads precede softmax_t's writes in program order, DS in-order)
    if (t > 0){
      if (!skp0){
        float ar[4];
#pragma unroll
        for (int r = 0; r < 4; ++r) ar[r] = __shfl(alp0, quad*4 + r);
#pragma unroll
        for (int dt = 0; dt < 8; ++dt)
#pragma unroll
          for (int r = 0; r < 4; ++r) oacc0[dt][r] *= ar[r];
      }
      if (!skp1){
        float ar[4];
#pragma unroll
        for (int r = 0; r < 4; ++r) ar[r] = __shfl(alp1, quad*4 + r);
#pragma unroll
        for (int dt = 0; dt < 8; ++dt)
#pragma unroll
          for (int r = 0; r < 4; ++r) oacc1[dt][r] *= ar[r];
      }
#pragma unroll
      for (int kc2 = 0; kc2 < 2; ++kc2){
        bf16x8 pa0 = *(bf16x8*)&Ps[(w*32 + l15)*VP + kc2*32 + quad*8];
        bf16x8 pa1 = *(bf16x8*)&Ps[(w*32 + 16 + l15)*VP + kc2*32 + quad*8];
        __builtin_amdgcn_s_setprio(1);
#pragma unroll
        for (int dt = 0; dt < 8; ++dt){
          bf16x8 vb8 = *(bf16x8*)((char*)&VTs[vprev][0] + (dt*16 + l15)*128
                                  + ((kc2*64 + quad*16) ^ xr));
          oacc0[dt] = __builtin_amdgcn_mfma_f32_16x16x32_bf16(pa0, vb8, oacc0[dt], 0, 0, 0);
          oacc1[dt] = __builtin_amdgcn_mfma_f32_16x16x32_bf16(pa1, vb8, oacc1[dt], 0, 0, 0);
        }
        __builtin_amdgcn_s_setprio(0);
      }
    }

    // ---- softmax_t (log2 domain; tree max/sum; defer-max) ----
    bool mlow  = (role == 1) && (kb == qb - 8);   // valid: key >= qi
    bool mhigh = (role == 1) && (kb == qb);       // valid: key <= qi
    bool domask = mlow | mhigh;

    auto softmax_qt = [&](f32x4* sc2, float& m1r, float& l1r, int qi_l,
                          bool& skipped) -> float {
      if (domask){
#pragma unroll
        for (int nt = 0; nt < 4; ++nt)
#pragma unroll
          for (int r = 0; r < 4; ++r){
            int key = nt*16 + quad*4 + r;
            bool valid = (!mlow || key >= qi_l) && (!mhigh || key <= qi_l);
            sc2[nt][r] = valid ? sc2[nt][r] : -INFINITY;
          }
      }
      float mnt[4];
#pragma unroll
      for (int nt = 0; nt < 4; ++nt)
        mnt[nt] = fmaxf(fmaxf(sc2[nt][0], sc2[nt][1]),
                        fmaxf(sc2[nt][2], sc2[nt][3]));
      float mx = fmaxf(fmaxf(mnt[0], mnt[1]), fmaxf(mnt[2], mnt[3]));
      mx = fmaxf(mx, __shfl_xor(mx, 16));
      mx = fmaxf(mx, __shfl_xor(mx, 32));
      float al = 1.f;
      skipped = __all(mx <= m1r + 8.f);     // defer-max: P bounded by 2^8
      if (!skipped){
        float mn = fmaxf(m1r, mx);
        al = exp2f(m1r - mn);
        m1r = mn;
      }
      float snt[4];
#pragma unroll
      for (int nt = 0; nt < 4; ++nt){
        float p0 = exp2f(sc2[nt][0] - m1r);
        float p1 = exp2f(sc2[nt][1] - m1r);
        float p2 = exp2f(sc2[nt][2] - m1r);
        float p3 = exp2f(sc2[nt][3] - m1r);
        sc2[nt][0] = p0; sc2[nt][1] = p1; sc2[nt][2] = p2; sc2[nt][3] = p3;
        snt[nt] = (p0 + p1) + (p2 + p3);
      }
      float s0 = (snt[0] + snt[1]) + (snt[2] + snt[3]);
      s0 += __shfl_xor(s0, 16);
      s0 += __shfl_xor(s0, 32);
      l1r = l1r*al + s0;
      return al;
    };
    bool sk0, sk1;
    float al0 = softmax_qt(sacc0, m10, l10, qi0, sk0);
    float al1 = softmax_qt(sacc1, m11, l11, qi1, sk1);
    alp0 = al0; skp0 = sk0;
    alp1 = al1; skp1 = sk1;

    // ---- P -> LDS bf16, packed b64 (row = query; wave-private slab) ----
#pragma unroll
    for (int nt = 0; nt < 4; ++nt){
      uint2 p0, p1;
      p0.x = pkbf(sacc0[nt][0], sacc0[nt][1]);
      p0.y = pkbf(sacc0[nt][2], sacc0[nt][3]);
      p1.x = pkbf(sacc1[nt][0], sacc1[nt][1]);
      p1.y = pkbf(sacc1[nt][2], sacc1[nt][3]);
      *(uint2*)&Ps[(w*32 + l15)*VP + nt*16 + quad*4] = p0;
      *(uint2*)&Ps[(w*32 + 16 + l15)*VP + nt*16 + quad*4] = p1;
    }

    int tmpv = vprev; vprev = vcur; vcur = vnext; vnext = tmpv;
  }

  // ---- drain: rescale + PV_{nph-1} ----
  {
    if (!skp0){
      float ar[4];
#pragma unroll
      for (int r = 0; r < 4; ++r) ar[r] = __shfl(alp0, quad*4 + r);
#pragma unroll
      for (int dt = 0; dt < 8; ++dt)
#pragma unroll
        for (int r = 0; r < 4; ++r) oacc0[dt][r] *= ar[r];
    }
    if (!skp1){
      float ar[4];
#pragma unroll
      for (int r = 0; r < 4; ++r) ar[r] = __shfl(alp1, quad*4 + r);
#pragma unroll
      for (int dt = 0; dt < 8; ++dt)
#pragma unroll
        for (int r = 0; r < 4; ++r) oacc1[dt][r] *= ar[r];
    }
#pragma unroll
    for (int kc2 = 0; kc2 < 2; ++kc2){
      bf16x8 pa0 = *(bf16x8*)&Ps[(w*32 + l15)*VP + kc2*32 + quad*8];
      bf16x8 pa1 = *(bf16x8*)&Ps[(w*32 + 16 + l15)*VP + kc2*32 + quad*8];
#pragma unroll
      for (int dt = 0; dt < 8; ++dt){
        bf16x8 vb8 = *(bf16x8*)((char*)&VTs[vprev][0] + (dt*16 + l15)*128
                                + ((kc2*64 + quad*16) ^ xr));
        oacc0[dt] = __builtin_amdgcn_mfma_f32_16x16x32_bf16(pa0, vb8, oacc0[dt], 0, 0, 0);
        oacc1[dt] = __builtin_amdgcn_mfma_f32_16x16x32_bf16(pa1, vb8, oacc1[dt], 0, 0, 0);
      }
    }
  }

  // ---- epilogue ----
  float lr0[4], lr1[4];
#pragma unroll
  for (int r = 0; r < 4; ++r){
    lr0[r] = __shfl(l10, quad*4 + r);
    lr1[r] = __shfl(l11, quad*4 + r);
  }
  if (role == 0){
    // fold slc gate + norm into oacc, then add cmp branch via hi/lo PV
    float a0[4], a1[4];
#pragma unroll
    for (int r = 0; r < 4; ++r){ a0[r] = gl0[r]/lr0[r]; a1[r] = gl1[r]/lr1[r]; }
#pragma unroll
    for (int dt = 0; dt < 8; ++dt)
#pragma unroll
      for (int r = 0; r < 4; ++r){ oacc0[dt][r] *= a0[r]; oacc1[dt][r] *= a1[r]; }
    // write cmp P (g0-scaled, hi/lo) into own wave slab; same-wave RAW only
#pragma unroll
    for (int nt = 0; nt < 2; ++nt){
      union { ushort_t u[4]; uint2 v; } h0, l0, h1, l1;
#pragma unroll
      for (int r = 0; r < 4; ++r){
        ushort_t hh0 = b16(cp0[nt][r]);
        h0.u[r] = hh0; l0.u[r] = b16(cp0[nt][r] - fb(hh0));
        ushort_t hh1 = b16(cp1[nt][r]);
        h1.u[r] = hh1; l1.u[r] = b16(cp1[nt][r] - fb(hh1));
      }
      *(uint2*)&Ps[(w*32 + l15)*VP + nt*16 + quad*4]      = h0.v;
      *(uint2*)&Ps[(w*32 + l15)*VP + 32 + nt*16 + quad*4] = l0.v;
      *(uint2*)&Ps[(w*32 + 16 + l15)*VP + nt*16 + quad*4]      = h1.v;
      *(uint2*)&Ps[(w*32 + 16 + l15)*VP + 32 + nt*16 + quad*4] = l1.v;
    }
    bf16x8 pah0 = *(bf16x8*)&Ps[(w*32 + l15)*VP + quad*8];
    bf16x8 pal0 = *(bf16x8*)&Ps[(w*32 + l15)*VP + 32 + quad*8];
    bf16x8 pah1 = *(bf16x8*)&Ps[(w*32 + 16 + l15)*VP + quad*8];
    bf16x8 pal1 = *(bf16x8*)&Ps[(w*32 + 16 + l15)*VP + 32 + quad*8];
#pragma unroll
    for (int dt = 0; dt < 8; ++dt){
      bf16x8 vbh = *(bf16x8*)&VcTh[(dt*16 + l15)*VCS + quad*8];
      bf16x8 vbl = *(bf16x8*)&VcTl[(dt*16 + l15)*VCS + quad*8];
      oacc0[dt] = __builtin_amdgcn_mfma_f32_16x16x32_bf16(pah0, vbh, oacc0[dt], 0, 0, 0);
      oacc0[dt] = __builtin_amdgcn_mfma_f32_16x16x32_bf16(pah0, vbl, oacc0[dt], 0, 0, 0);
      oacc0[dt] = __builtin_amdgcn_mfma_f32_16x16x32_bf16(pal0, vbh, oacc0[dt], 0, 0, 0);
      oacc1[dt] = __builtin_amdgcn_mfma_f32_16x16x32_bf16(pah1, vbh, oacc1[dt], 0, 0, 0);
      oacc1[dt] = __builtin_amdgcn_mfma_f32_16x16x32_bf16(pah1, vbl, oacc1[dt], 0, 0, 0);
      oacc1[dt] = __builtin_amdgcn_mfma_f32_16x16x32_bf16(pal1, vbh, oacc1[dt], 0, 0, 0);
    }
#pragma unroll
    for (int r = 0; r < 4; ++r){
      size_t ob0 = ((size_t)(bb*SEQ + qb*64 + qh2*32 + quad*4 + r)*QH + g*NH + h)*DIM + l15;
      size_t ob1 = ob0 + (size_t)16*QH*DIM;
      float* op0 = slcbuf + ob0;            // unique writer; full coverage
      float* op1 = slcbuf + ob1;
#pragma unroll
      for (int dt = 0; dt < 8; ++dt){
        op0[dt*16] = oacc0[dt][r];
        op1[dt*16] = oacc1[dt][r];
      }
    }
  } else {
#pragma unroll
    for (int r = 0; r < 4; ++r){
      float s20 = gl0[r] / lr0[r];
      float s21 = gl1[r] / lr1[r];
      size_t ob0 = ((size_t)(bb*SEQ + qb*64 + qh2*32 + quad*4 + r)*QH + g*NH + h)*DIM + l15;
      size_t ob1 = ob0 + (size_t)16*QH*DIM;
      float* op0 = out + ob0;               // unique writer; OVERWRITE
      float* op1 = out + ob1;
#pragma unroll
      for (int dt = 0; dt < 8; ++dt){
        op0[dt*16] = s20 * oacc0[dt][r];
        op1[dt*16] = s21 * oacc1[dt][r];
      }
    }
  }
}

// ---------------- kernel 2: merge (out += slcbuf) ---------------------------
__global__ __launch_bounds__(256) void merge_k(const float* __restrict__ slcbuf,
                                               float* __restrict__ out){
  int i = blockIdx.x * 256 + threadIdx.x;   // over 4096*8*128/4 float4s
  float4 a = ((const float4*)slcbuf)[i];
  float4 b = ((float4*)out)[i];
  b.x += a.x; b.y += a.y; b.z += a.z; b.w += a.w;
  ((float4*)out)[i] = b;
}

extern "C" void kernel_launch(void* const* d_in, const int* in_sizes, int n_in,
                              void* d_out, int out_size, void* d_ws, size_t ws_size,
                              hipStream_t stream) {
  const float* q      = (const float*)d_in[0];
  const float* k      = (const float*)d_in[1];
  const float* v      = (const float*)d_in[2];
  const float* w_k    = (const float*)d_in[3];
  const float* b_k    = (const float*)d_in[4];
  const float* w_v    = (const float*)d_in[5];
  const float* b_v    = (const float*)d_in[6];
  const float* w_gate = (const float*)d_in[7];
  const float* b_gate = (const float*)d_in[8];
  float* out = (float*)d_out;

  float* ws     = (float*)d_ws;
  float* Kc     = ws;                        // 16384 f32
  float* Vc     = ws + 16384;                // 16384 f32
  float* slcbuf = ws + 49152;                // 4.19M f32 (16.8 MB)
  ushort_t* Kb  = (ushort_t*)(ws + 4243456); // 4*2048*128 bf16 (2 MB)
  ushort_t* VT  = Kb + 1048576;              // 4*128*2048 bf16 (2 MB)

  prep_k <<<256, 256, 0, stream>>>(k, v, w_k, b_k, w_v, b_v, Kb, VT, Kc, Vc);
  attn_k <<<256, 512, 0, stream>>>(q, Kb, VT, Kc, Vc, w_gate, b_gate, slcbuf, out);
  merge_k<<<4096, 256, 0, stream>>>(slcbuf, out);
}